// Round 18
// baseline (575.688 us; speedup 1.0000x reference)
//
#include <hip/hip_runtime.h>

using bf16   = __bf16;
using bf16x4 = __bf16 __attribute__((ext_vector_type(4)));
using bf16x8 = __bf16 __attribute__((ext_vector_type(8)));
using f32x4  = float __attribute__((ext_vector_type(4)));

#define MFMA_BF16(a, b, c) __builtin_amdgcn_mfma_f32_16x16x32_bf16((a), (b), (c), 0, 0, 0)

constexpr int BATCH = 64, SEQ = 257, DIM = 768, NH = 12;
constexpr size_t WE = (size_t)DIM * DIM;

__device__ inline void gload_lds16(const bf16* g, bf16* l) {
  __builtin_amdgcn_global_load_lds(
      (const __attribute__((address_space(1))) void*)g,
      (__attribute__((address_space(3))) void*)l, 16, 0, 0);
}

// ---------------- weight fp32 -> bf16 ----------------
__global__ __launch_bounds__(256) void cvt_weights(
    const float* __restrict__ wq, const float* __restrict__ wk,
    const float* __restrict__ wv, const float* __restrict__ wo,
    bf16* __restrict__ dst) {
  const size_t i = (size_t)blockIdx.x * 256 + threadIdx.x;  // float4 index
  const size_t per = WE / 4;
  if (i >= 4 * per) return;
  const float* srcs[4] = {wq, wk, wv, wo};
  const float4 f = ((const float4*)srcs[i / per])[i % per];
  bf16* o = dst + i * 4;
  o[0] = (bf16)f.x; o[1] = (bf16)f.y; o[2] = (bf16)f.z; o[3] = (bf16)f.w;
}

// ---------------- hs fp32 -> bf16 ----------------
__global__ __launch_bounds__(256) void cvt_hs(const float* __restrict__ src,
                                              bf16* __restrict__ dst, int n4) {
  const int i = blockIdx.x * 256 + threadIdx.x;
  if (i >= n4) return;
  const float4 f = ((const float4*)src)[i];
  bf16* o = dst + (size_t)i * 4;
  o[0] = (bf16)f.x; o[1] = (bf16)f.y; o[2] = (bf16)f.z; o[3] = (bf16)f.w;
}

// ---------------- depthwise conv + cls concat -> xb bf16 [B][L][768] ----------------
template <int KS>
__global__ __launch_bounds__(256) void conv_kernel(
    const float* __restrict__ hs, const float* __restrict__ cw, bf16* __restrict__ xb) {
  constexpr int OW = 17 - KS;
  constexpr int NOUT = OW * OW;
  constexpr int L = NOUT + 1;
  constexpr int KSQ = KS * KS;
  constexpr int NP = (NOUT + 7) / 8;
  __shared__ float hsl[256][36];
  __shared__ float wsm[32][KSQ];

  const int t = threadIdx.x;
  const int b = blockIdx.y;
  const int c0 = blockIdx.x * 32;

  const float* src = hs + ((size_t)b * SEQ + 1 + t) * DIM + c0;
#pragma unroll
  for (int j = 0; j < 8; ++j) *(float4*)&hsl[t][4 * j] = ((const float4*)src)[j];

  if (t < 32) {
#pragma unroll
    for (int q = 0; q < KSQ; ++q) wsm[t][q] = cw[(size_t)(c0 + t) * KSQ + q];
    const float cv = hs[(size_t)b * SEQ * DIM + c0 + t];
    xb[(size_t)b * L * DIM + c0 + t] = (bf16)cv;
  }
  __syncthreads();

  const int c = t & 31, pg = t >> 5;
#pragma unroll
  for (int i = 0; i < NP; ++i) {
    const int p = pg * NP + i;
    if (p < NOUT) {
      const int oi = p / OW, oj = p - oi * OW;
      float a = 0.f;
#pragma unroll
      for (int di = 0; di < KS; ++di)
#pragma unroll
        for (int dj = 0; dj < KS; ++dj)
          a += hsl[(oi + di) * 16 + oj + dj][c] * wsm[c][di * KS + dj];
      xb[((size_t)b * L + 1 + p) * DIM + c0 + c] = (bf16)a;
    }
  }
}

// ---------------- unified GEMM: Y = A @ W^T + bias (128x128 tile, BK=32) ----------------
// Wait-depth-2 pipeline: 4 LDS buffers, prologue stages tiles 0-2, each iter stages
// kt+3 then waits vmcnt(8) -> awaited tile was issued TWO iterations (~1700cy) ago,
// covering the ~900cy HBM latency (r17: wait-depth-1 pinned iter time at HBM latency).
// LDS chunk-swizzled both sides (r15/r17: conflicts 13x down). Epilogue via LDS.
// OUT: 0 = Q->qb bf16 [B][H][257][64] (x0.125)
//      1 = fused KV (N=1536): tN<6 -> K [B][H][L][64] chunk-XOR-swizzled (chunk^=l&7);
//          tN>=6 -> V [B][H][64][Lv] transposed
//      3 = fp32 [M][768]
template <int OUT>
__global__ __launch_bounds__(256, 4) void gemm_lds_kernel(
    const bf16* __restrict__ A, const bf16* __restrict__ W,
    const float* __restrict__ bias0, const float* __restrict__ bias1,
    void* __restrict__ Y0, void* __restrict__ Y1, int M, int L, int Lv, int nN) {
  constexpr int BUF_E = 128 * 32;                 // 4096 elems = 8 KB per buffer
  __shared__ alignas(16) bf16 sm[8 * BUF_E];      // 4x A | 4x B = 64 KB; reused by epilogue
  bf16* smA = sm;
  bf16* smB = sm + 4 * BUF_E;

  const int tid = threadIdx.x;
  const int lane = tid & 63;
  const int w = tid >> 6;

  // m204 bijective XCD swizzle; logical order = tN-major within tM
  const int nwg = gridDim.x;
  const int orig = blockIdx.x;
  const int nq = nwg >> 3, rr = nwg & 7, xcd = orig & 7, base = orig >> 3;
  const int wgid = (xcd < rr ? xcd * (nq + 1) : rr * (nq + 1) + (xcd - rr) * nq) + base;
  const int tM = wgid / nN, tN = wgid - tM * nN;

  const int wr = (w >> 1) * 64, wc = (w & 1) * 64;
  const int rl = lane & 15;
  const int g = lane >> 4;
  const int kqs = ((g ^ ((rl >> 1) & 3)) << 3);  // read-side chunk deswizzle

  // staging: wave w DMAs rows [w*32, w*32+32); global chunk pre-swizzled (dest linear)
  const int sr = lane >> 2;
  const int sk = (((lane & 3) ^ ((sr >> 1) & 3)) << 3);
  const int r0 = w * 32 + sr;
  const int r1 = w * 32 + 16 + sr;
  long ga0 = (long)tM * 128 + r0; if (ga0 >= M) ga0 = M - 1;
  long ga1 = (long)tM * 128 + r1; if (ga1 >= M) ga1 = M - 1;
  const bf16* pa0 = A + ga0 * DIM + sk;
  const bf16* pa1 = A + ga1 * DIM + sk;
  const bf16* pb0 = W + ((size_t)tN * 128 + r0) * DIM + sk;
  const bf16* pb1 = W + ((size_t)tN * 128 + r1) * DIM + sk;
  const int lbase = (w * 32) * 32;  // wave-uniform LDS elem offset

  const f32x4 zero4 = {0.f, 0.f, 0.f, 0.f};
  f32x4 acc[4][4];
#pragma unroll
  for (int m = 0; m < 4; ++m)
#pragma unroll
    for (int n = 0; n < 4; ++n) acc[m][n] = zero4;

  constexpr int NT = DIM / 32;  // 24 K-steps

#define STAGE(kt_, buf_)                                      \
  do {                                                        \
    const int kb_ = (kt_) * 32;                               \
    bf16* a_ = smA + (buf_) * BUF_E + lbase;                  \
    bf16* b_ = smB + (buf_) * BUF_E + lbase;                  \
    gload_lds16(pa0 + kb_, a_);                               \
    gload_lds16(pa1 + kb_, a_ + 512);                         \
    gload_lds16(pb0 + kb_, b_);                               \
    gload_lds16(pb1 + kb_, b_ + 512);                         \
  } while (0)

  // prologue: tiles 0,1,2 in flight (12 loads); wait tile 0 only
  STAGE(0, 0);
  STAGE(1, 1);
  STAGE(2, 2);
  asm volatile("s_waitcnt vmcnt(8)" ::: "memory");
  __builtin_amdgcn_s_barrier();
  __builtin_amdgcn_sched_barrier(0);

  int buf = 0;
  for (int kt = 0; kt < NT; ++kt) {
    const bf16* Ac = smA + buf * BUF_E;
    const bf16* Bc = smB + buf * BUF_E;
    bf16x8 af[4], bfr[4];
#pragma unroll
    for (int m = 0; m < 4; ++m) af[m] = *(const bf16x8*)&Ac[(wr + m * 16 + rl) * 32 + kqs];
#pragma unroll
    for (int n = 0; n < 4; ++n) bfr[n] = *(const bf16x8*)&Bc[(wc + n * 16 + rl) * 32 + kqs];
#pragma unroll
    for (int m = 0; m < 4; ++m)
#pragma unroll
      for (int n = 0; n < 4; ++n) acc[m][n] = MFMA_BF16(af[m], bfr[n], acc[m][n]);

    if (kt + 3 < NT) {
      STAGE(kt + 3, (buf + 3) & 3);  // tile kt+3 reuses buffer of tile kt-1 (done pre-barrier)
    }
    if (kt + 3 < NT)      asm volatile("s_waitcnt vmcnt(8)" ::: "memory");  // tile kt+1 landed
    else if (kt + 2 < NT) asm volatile("s_waitcnt vmcnt(4)" ::: "memory");
    else if (kt + 1 < NT) asm volatile("s_waitcnt vmcnt(0)" ::: "memory");
    if (kt + 1 < NT) {
      __builtin_amdgcn_s_barrier();
      __builtin_amdgcn_sched_barrier(0);
    }
    buf = (buf + 1) & 3;
  }
#undef STAGE

  // ---------------- epilogue ----------------
  if constexpr (OUT == 3) {
#pragma unroll
    for (int n = 0; n < 4; ++n) {
      const int gcol = tN * 128 + wc + n * 16 + rl;
      const float bia = bias0[gcol];
#pragma unroll
      for (int m = 0; m < 4; ++m) {
#pragma unroll
        for (int i = 0; i < 4; ++i) {
          const long grow = (long)tM * 128 + wr + m * 16 + g * 4 + i;
          if (grow < M) ((float*)Y0)[grow * DIM + gcol] = acc[m][n][i] + bia;
        }
      }
    }
    return;
  }

  constexpr int TP = 136;  // padded stride for the 128x128 bf16 staging tile
  bf16* smT = sm;          // 128*136*2 = 34.8 KB < 64 KB
  __syncthreads();         // all compute + DMA done; sm safe to reuse

  const bool vpath = (OUT == 1) && (tN >= 6);
  if (vpath) {
    // store transposed: smT[col*TP + row] so writeback is contiguous along l
#pragma unroll
    for (int n = 0; n < 4; ++n) {
      const int col = wc + n * 16 + rl;
      const float bia = bias1[tN * 128 + col - 768];
#pragma unroll
      for (int m = 0; m < 4; ++m) {
        const int row = wr + m * 16 + g * 4;
        bf16x4 v4;
#pragma unroll
        for (int i = 0; i < 4; ++i) v4[i] = (bf16)(acc[m][n][i] + bia);
        *(bf16x4*)(smT + col * TP + row) = v4;
      }
    }
    __syncthreads();
    bf16* vout = (bf16*)Y1;
    const int tNv = tN - 6;
#pragma unroll
    for (int it = 0; it < 8; ++it) {
      const int c = it * 256 + tid;
      const int coll = c >> 4;
      const int rw0 = (c & 15) * 8;
      const long g2 = (long)tM * 128 + rw0;
      if (g2 < M) {
        const int b2 = (int)(g2 / L);
        const int l2 = (int)(g2 - (long)b2 * L);
        const int cv = tNv * 128 + coll;
        bf16* dst = vout + (((size_t)b2 * NH + (cv >> 6)) * 64 + (cv & 63)) * Lv;
        const bf16x8 v = *(const bf16x8*)(smT + coll * TP + rw0);
        if (l2 + 8 <= L) {
          *(bf16x8*)(dst + l2) = v;
        } else {  // chunk crosses a batch boundary
#pragma unroll
          for (int j = 0; j < 8; ++j) {
            const long g3 = g2 + j;
            const int b3 = (int)(g3 / L), l3 = (int)(g3 - (long)b3 * L);
            vout[(((size_t)b3 * NH + (cv >> 6)) * 64 + (cv & 63)) * Lv + l3] = v[j];
          }
        }
      }
    }
  } else {
    // Q / K: smT[row*TP + col], writeback contiguous along col
    const float scale = (OUT == 0) ? 0.125f : 1.f;
#pragma unroll
    for (int n = 0; n < 4; ++n) {
      const int col = wc + n * 16 + rl;
      const float bia = bias0[tN * 128 + col];
#pragma unroll
      for (int m = 0; m < 4; ++m) {
#pragma unroll
        for (int i = 0; i < 4; ++i) {
          const int row = wr + m * 16 + g * 4 + i;
          smT[row * TP + col] = (bf16)((acc[m][n][i] + bia) * scale);
        }
      }
    }
    __syncthreads();
    bf16* kout = (bf16*)Y0;
#pragma unroll
    for (int it = 0; it < 8; ++it) {
      const int c = it * 256 + tid;
      const int row = c >> 4;
      const int col0 = (c & 15) * 8;
      const long g2 = (long)tM * 128 + row;
      if (g2 < M) {
        const int b2 = (int)(g2 / L);
        const int l2 = (int)(g2 - (long)b2 * L);
        const int gc = tN * 128 + col0;
        const bf16x8 v = *(const bf16x8*)(smT + row * TP + col0);
        int dchunk = (gc & 63) >> 3;
        if constexpr (OUT == 1) dchunk ^= (l2 & 7);  // pre-swizzle K's global layout
        *(bf16x8*)(kout + (((size_t)b2 * NH + (gc >> 6)) * L + l2) * 64 + dchunk * 8) = v;
      }
    }
  }
}

// ---------------- fused attention: one block per (b,h), loops over 5 q-tiles ----------------
// K staged ONCE per bh via global_load_lds (was 5x in r17: FETCH 56 MB), then all 5
// q-tiles consume it. Ks read-only after the single barrier; Ps rows wave-private.
// Max-free single-pass softmax; V from global with 2-deep ring.
template <int L, int BRANCH>
__global__ __launch_bounds__(256, 2) void attn_kernel(
    const bf16* __restrict__ qb, const bf16* __restrict__ kb, const bf16* __restrict__ vb,
    float* __restrict__ ctx, bf16* __restrict__ xbuf, int Lv) {
  constexpr int LK16 = (L + 15) & ~15;
  constexpr int NKT = LK16 / 16;
  constexpr int LP32 = (L + 31) & ~31;
  constexpr int NK32 = LP32 / 32;
  constexpr int PSTR = LP32 + 8;
  __shared__ alignas(16) bf16 Ks[LK16 * 64];  // swizzled rows (as stored in global)
  __shared__ alignas(16) bf16 Ps[64 * PSTR];

  const int tid = threadIdx.x, lane = tid & 63, w = tid >> 6;
  // XCD swizzle: gridDim.x = 768 = 8*96
  const int orig = blockIdx.x;
  const int nper = gridDim.x >> 3;
  const int bh = (orig & 7) * nper + (orig >> 3);
  const int b = bh / NH, h = bh % NH;
  const int cl = lane & 15, g = lane >> 4;

  // ---- DMA-stage K once: linear copy (global pre-swizzled); tail rows garbage ----
  const bf16* kbase = kb + (size_t)bh * L * 64;
  for (int c = tid; c < LK16 * 8; c += 256)
    gload_lds16(kbase + (size_t)c * 8, Ks + (size_t)c * 8);
  __syncthreads();  // drains K-DMA + visibility for all waves

  const bf16* vbase = vb + (size_t)bh * 64 * Lv;

  for (int qt = 0; qt < 5; ++qt) {
    int sq = qt * 64 + w * 16 + cl;
    if (sq > 256) sq = 256;
    const bf16* qrow = qb + ((size_t)bh * 257 + sq) * 64 + g * 8;
    const bf16x8 aq0 = *(const bf16x8*)qrow;
    const bf16x8 aq1 = *(const bf16x8*)(qrow + 32);

    // ---- fused QK^T + exp + P-store (scale folded into Q) ----
    float sums[4] = {0.f, 0.f, 0.f, 0.f};
    const int prow0 = (w * 16 + g * 4) * PSTR + cl;  // row q = w*16+g*4+j
#pragma unroll
    for (int kt = 0; kt < NKT; ++kt) {
      const int key0 = kt * 16 + cl;
      const int sw = key0 & 7;
      const char* krow = (const char*)Ks + key0 * 128;
      const bf16x8 bk0 = *(const bf16x8*)(krow + ((g ^ sw) << 4));
      const bf16x8 bk1 = *(const bf16x8*)(krow + (((4 + g) ^ sw) << 4));
      f32x4 z = {0.f, 0.f, 0.f, 0.f};
      z = MFMA_BF16(aq0, bk0, z);
      z = MFMA_BF16(aq1, bk1, z);
      const bool valid = key0 < L;
#pragma unroll
      for (int j = 0; j < 4; ++j) {
        const float p = valid ? __expf(z[j]) : 0.f;  // |s| small: max-free softmax
        sums[j] += p;
        Ps[prow0 + j * PSTR + kt * 16] = (bf16)p;
      }
    }
    if constexpr (LP32 > LK16) {
#pragma unroll
      for (int j = 0; j < 4; ++j) Ps[prow0 + j * PSTR + LK16] = (bf16)0.f;
    }

    // ---- T14: first V-group issued before the sum reduction ----
    bf16x8 vr0[4], vr1[4];
#pragma unroll
    for (int nt = 0; nt < 4; ++nt)
      vr0[nt] = *(const bf16x8*)(vbase + (size_t)(nt * 16 + cl) * Lv + g * 8);

#pragma unroll
    for (int j = 0; j < 4; ++j) {
      sums[j] += __shfl_xor(sums[j], 1);
      sums[j] += __shfl_xor(sums[j], 2);
      sums[j] += __shfl_xor(sums[j], 4);
      sums[j] += __shfl_xor(sums[j], 8);
    }
    float inv[4];
#pragma unroll
    for (int j = 0; j < 4; ++j) inv[j] = 1.f / sums[j];
    // no barrier: each wave reads only its own 16 Ps rows (same-wave DS ordering)

    // ---- PV with 2-deep V ring; normalization applied at the store ----
    f32x4 cacc[4];
#pragma unroll
    for (int nt = 0; nt < 4; ++nt) cacc[nt] = f32x4{0.f, 0.f, 0.f, 0.f};
#pragma unroll
    for (int kt = 0; kt < NK32; ++kt) {
      const bool even = (kt & 1) == 0;
      if (kt + 1 < NK32) {
        int kk = (kt + 1) * 32 + g * 8;
        if (kk > Lv - 8) kk = Lv - 8;  // clamp: only P==0 keys affected
#pragma unroll
        for (int nt = 0; nt < 4; ++nt) {
          const bf16x8 v = *(const bf16x8*)(vbase + (size_t)(nt * 16 + cl) * Lv + kk);
          if (even) vr1[nt] = v; else vr0[nt] = v;
        }
      }
      const bf16x8 ap = *(const bf16x8*)&Ps[(w * 16 + cl) * PSTR + kt * 32 + g * 8];
#pragma unroll
      for (int nt = 0; nt < 4; ++nt)
        cacc[nt] = MFMA_BF16(ap, even ? vr0[nt] : vr1[nt], cacc[nt]);
    }

#pragma unroll
    for (int nt = 0; nt < 4; ++nt) {
#pragma unroll
      for (int i = 0; i < 4; ++i) {
        const int s_q = qt * 64 + w * 16 + g * 4 + i;
        if (s_q < 257) {
          const size_t idx = ((size_t)b * 257 + s_q) * DIM + h * 64 + nt * 16 + cl;
          const float val = cacc[nt][i] * inv[i];
          if constexpr (BRANCH == 0)
            ctx[idx] = val;
          else if constexpr (BRANCH == 1)
            ctx[idx] += val;
          else
            xbuf[idx] = (bf16)((ctx[idx] + val) * (1.f / 3.f));
        }
      }
    }
  }
}

extern "C" void kernel_launch(void* const* d_in, const int* in_sizes, int n_in,
                              void* d_out, int out_size, void* d_ws, size_t ws_size,
                              hipStream_t stream) {
  (void)in_sizes; (void)n_in; (void)out_size; (void)ws_size;
  const float* hs = (const float*)d_in[0];
  const float* Wq = (const float*)d_in[1];
  const float* bq = (const float*)d_in[2];
  const float* Wk = (const float*)d_in[3];
  const float* bk = (const float*)d_in[4];
  const float* Wv = (const float*)d_in[5];
  const float* bv = (const float*)d_in[6];
  const float* Wo = (const float*)d_in[7];
  const float* bo = (const float*)d_in[8];
  const float* c1 = (const float*)d_in[9];
  const float* c2 = (const float*)d_in[10];
  const float* c3 = (const float*)d_in[11];
  float* out = (float*)d_out;

  constexpr size_t QB = (size_t)BATCH * NH * SEQ * 64;
  constexpr size_t XB = (size_t)BATCH * SEQ * DIM;
  constexpr size_t K1 = (size_t)BATCH * NH * 257 * 64;

  bf16* wbf = (bf16*)d_ws;                          // [Wq|Wk|Wv|Wo] bf16
  bf16* qb = wbf + 4 * WE;                          // [B][H][257][64]
  bf16* xb = qb + QB;                               // [B][Lmax][768]; aliases hsb before conv1
  bf16* kbf = xb + XB;                              // [B][H][L][64], chunk-swizzled
  bf16* vbf = kbf + K1;                             // [B][H][64][Lv<=264]
  bf16* hsb = xb;

  cvt_weights<<<dim3((unsigned)((4 * WE / 4 + 255) / 256)), 256, 0, stream>>>(Wq, Wk, Wv, Wo, wbf);
  cvt_hs<<<dim3((BATCH * SEQ * DIM / 4 + 255) / 256), 256, 0, stream>>>(hs, hsb, BATCH * SEQ * DIM / 4);

  // Q projection (scale 1/8 folded), from bf16 hs
  gemm_lds_kernel<0><<<dim3(129 * 6), 256, 0, stream>>>(hsb, wbf, bq, bq, qb, qb, BATCH * SEQ, 257, 1, 6);

  // ---- branch 0: 1x1 conv, L=257 ----
  conv_kernel<1><<<dim3(24, 64), 256, 0, stream>>>(hs, c1, xb);
  gemm_lds_kernel<1><<<dim3(129 * 12), 256, 0, stream>>>(xb, wbf + WE, bk, bv, kbf, vbf, BATCH * 257, 257, 264, 12);
  attn_kernel<257, 0><<<dim3(768), 256, 0, stream>>>(qb, kbf, vbf, out, xb, 264);

  // ---- branch 1: 3x3 conv, L=197 ----
  conv_kernel<3><<<dim3(24, 64), 256, 0, stream>>>(hs, c2, xb);
  gemm_lds_kernel<1><<<dim3(99 * 12), 256, 0, stream>>>(xb, wbf + WE, bk, bv, kbf, vbf, BATCH * 197, 197, 200, 12);
  attn_kernel<197, 1><<<dim3(768), 256, 0, stream>>>(qb, kbf, vbf, out, xb, 200);

  // ---- branch 2: 5x5 conv, L=145 ----
  conv_kernel<5><<<dim3(24, 64), 256, 0, stream>>>(hs, c3, xb);
  gemm_lds_kernel<1><<<dim3(73 * 12), 256, 0, stream>>>(xb, wbf + WE, bk, bv, kbf, vbf, BATCH * 145, 145, 152, 12);
  attn_kernel<145, 2><<<dim3(768), 256, 0, stream>>>(qb, kbf, vbf, out, xb, 152);

  // ---- output projection: out = bf16(ctx/3) @ Wo^T + bo ----
  gemm_lds_kernel<3><<<dim3(129 * 6), 256, 0, stream>>>(xb, wbf + 3 * WE, bo, bo, out, out, BATCH * SEQ, 257, 1, 6);
}

// Round 19
// 527.515 us; speedup vs baseline: 1.0913x; 1.0913x over previous
//
#include <hip/hip_runtime.h>

using bf16   = __bf16;
using bf16x4 = __bf16 __attribute__((ext_vector_type(4)));
using bf16x8 = __bf16 __attribute__((ext_vector_type(8)));
using f32x4  = float __attribute__((ext_vector_type(4)));

#define MFMA_BF16(a, b, c) __builtin_amdgcn_mfma_f32_16x16x32_bf16((a), (b), (c), 0, 0, 0)

constexpr int BATCH = 64, SEQ = 257, DIM = 768, NH = 12;
constexpr size_t WE = (size_t)DIM * DIM;

__device__ inline void gload_lds16(const bf16* g, bf16* l) {
  __builtin_amdgcn_global_load_lds(
      (const __attribute__((address_space(1))) void*)g,
      (__attribute__((address_space(3))) void*)l, 16, 0, 0);
}

// ---------------- weight fp32 -> bf16 ----------------
__global__ __launch_bounds__(256) void cvt_weights(
    const float* __restrict__ wq, const float* __restrict__ wk,
    const float* __restrict__ wv, const float* __restrict__ wo,
    bf16* __restrict__ dst) {
  const size_t i = (size_t)blockIdx.x * 256 + threadIdx.x;  // float4 index
  const size_t per = WE / 4;
  if (i >= 4 * per) return;
  const float* srcs[4] = {wq, wk, wv, wo};
  const float4 f = ((const float4*)srcs[i / per])[i % per];
  bf16* o = dst + i * 4;
  o[0] = (bf16)f.x; o[1] = (bf16)f.y; o[2] = (bf16)f.z; o[3] = (bf16)f.w;
}

// ---------------- hs fp32 -> bf16 ----------------
__global__ __launch_bounds__(256) void cvt_hs(const float* __restrict__ src,
                                              bf16* __restrict__ dst, int n4) {
  const int i = blockIdx.x * 256 + threadIdx.x;
  if (i >= n4) return;
  const float4 f = ((const float4*)src)[i];
  bf16* o = dst + (size_t)i * 4;
  o[0] = (bf16)f.x; o[1] = (bf16)f.y; o[2] = (bf16)f.z; o[3] = (bf16)f.w;
}

// ---------------- depthwise conv + cls concat -> xb bf16 [B][L][768] ----------------
template <int KS>
__global__ __launch_bounds__(256) void conv_kernel(
    const float* __restrict__ hs, const float* __restrict__ cw, bf16* __restrict__ xb) {
  constexpr int OW = 17 - KS;
  constexpr int NOUT = OW * OW;
  constexpr int L = NOUT + 1;
  constexpr int KSQ = KS * KS;
  constexpr int NP = (NOUT + 7) / 8;
  __shared__ float hsl[256][36];
  __shared__ float wsm[32][KSQ];

  const int t = threadIdx.x;
  const int b = blockIdx.y;
  const int c0 = blockIdx.x * 32;

  const float* src = hs + ((size_t)b * SEQ + 1 + t) * DIM + c0;
#pragma unroll
  for (int j = 0; j < 8; ++j) *(float4*)&hsl[t][4 * j] = ((const float4*)src)[j];

  if (t < 32) {
#pragma unroll
    for (int q = 0; q < KSQ; ++q) wsm[t][q] = cw[(size_t)(c0 + t) * KSQ + q];
    const float cv = hs[(size_t)b * SEQ * DIM + c0 + t];
    xb[(size_t)b * L * DIM + c0 + t] = (bf16)cv;
  }
  __syncthreads();

  const int c = t & 31, pg = t >> 5;
#pragma unroll
  for (int i = 0; i < NP; ++i) {
    const int p = pg * NP + i;
    if (p < NOUT) {
      const int oi = p / OW, oj = p - oi * OW;
      float a = 0.f;
#pragma unroll
      for (int di = 0; di < KS; ++di)
#pragma unroll
        for (int dj = 0; dj < KS; ++dj)
          a += hsl[(oi + di) * 16 + oj + dj][c] * wsm[c][di * KS + dj];
      xb[((size_t)b * L + 1 + p) * DIM + c0 + c] = (bf16)a;
    }
  }
}

// ---------------- unified GEMM: Y = A @ W^T + bias (128x128 tile, BK=32) ----------------
// r17 structure (measured 86us, 3 blocks/CU): 3 LDS buffers, stage kt+2 while computing kt,
// s_waitcnt vmcnt(4) + raw s_barrier per K-step. [r18 lesson: 4-buf depth-2 costs a
// block of occupancy (64KB LDS -> 2/CU) and nets -35%; do not re-try at this tile size.]
// LDS chunk-swizzled both sides (conflicts 13x down, r17). Epilogue via LDS.
// OUT: 0 = Q->qb bf16 [B][H][257][64] (x0.125)
//      1 = fused KV (N=1536): tN<6 -> K [B][H][L][64] chunk-XOR-swizzled (chunk^=l&7);
//          tN>=6 -> V [B][H][64][Lv] transposed
//      3 = fp32 [M][768]
template <int OUT>
__global__ __launch_bounds__(256, 4) void gemm_lds_kernel(
    const bf16* __restrict__ A, const bf16* __restrict__ W,
    const float* __restrict__ bias0, const float* __restrict__ bias1,
    void* __restrict__ Y0, void* __restrict__ Y1, int M, int L, int Lv, int nN) {
  constexpr int BUF_E = 128 * 32;                 // 4096 elems = 8 KB per buffer
  __shared__ alignas(16) bf16 sm[6 * BUF_E];      // 3x A | 3x B = 48 KB; reused by epilogue
  bf16* smA = sm;
  bf16* smB = sm + 3 * BUF_E;

  const int tid = threadIdx.x;
  const int lane = tid & 63;
  const int w = tid >> 6;

  // m204 bijective XCD swizzle; logical order = tN-major within tM
  const int nwg = gridDim.x;
  const int orig = blockIdx.x;
  const int nq = nwg >> 3, rr = nwg & 7, xcd = orig & 7, base = orig >> 3;
  const int wgid = (xcd < rr ? xcd * (nq + 1) : rr * (nq + 1) + (xcd - rr) * nq) + base;
  const int tM = wgid / nN, tN = wgid - tM * nN;

  const int wr = (w >> 1) * 64, wc = (w & 1) * 64;
  const int rl = lane & 15;
  const int g = lane >> 4;
  const int kqs = ((g ^ ((rl >> 1) & 3)) << 3);  // read-side chunk deswizzle

  // staging: wave w DMAs rows [w*32, w*32+32); global chunk pre-swizzled (dest linear)
  const int sr = lane >> 2;
  const int sk = (((lane & 3) ^ ((sr >> 1) & 3)) << 3);
  const int r0 = w * 32 + sr;
  const int r1 = w * 32 + 16 + sr;
  long ga0 = (long)tM * 128 + r0; if (ga0 >= M) ga0 = M - 1;
  long ga1 = (long)tM * 128 + r1; if (ga1 >= M) ga1 = M - 1;
  const bf16* pa0 = A + ga0 * DIM + sk;
  const bf16* pa1 = A + ga1 * DIM + sk;
  const bf16* pb0 = W + ((size_t)tN * 128 + r0) * DIM + sk;
  const bf16* pb1 = W + ((size_t)tN * 128 + r1) * DIM + sk;
  const int lbase = (w * 32) * 32;  // wave-uniform LDS elem offset

  const f32x4 zero4 = {0.f, 0.f, 0.f, 0.f};
  f32x4 acc[4][4];
#pragma unroll
  for (int m = 0; m < 4; ++m)
#pragma unroll
    for (int n = 0; n < 4; ++n) acc[m][n] = zero4;

  constexpr int NT = DIM / 32;  // 24 K-steps

#define STAGE(kt_, buf_)                                      \
  do {                                                        \
    const int kb_ = (kt_) * 32;                               \
    bf16* a_ = smA + (buf_) * BUF_E + lbase;                  \
    bf16* b_ = smB + (buf_) * BUF_E + lbase;                  \
    gload_lds16(pa0 + kb_, a_);                               \
    gload_lds16(pa1 + kb_, a_ + 512);                         \
    gload_lds16(pb0 + kb_, b_);                               \
    gload_lds16(pb1 + kb_, b_ + 512);                         \
  } while (0)

  // prologue: tiles 0 and 1 in flight; wait tile 0 only
  STAGE(0, 0);
  STAGE(1, 1);
  asm volatile("s_waitcnt vmcnt(4)" ::: "memory");
  __builtin_amdgcn_s_barrier();
  __builtin_amdgcn_sched_barrier(0);

  int buf = 0;
  for (int kt = 0; kt < NT; ++kt) {
    const bf16* Ac = smA + buf * BUF_E;
    const bf16* Bc = smB + buf * BUF_E;
    bf16x8 af[4], bfr[4];
#pragma unroll
    for (int m = 0; m < 4; ++m) af[m] = *(const bf16x8*)&Ac[(wr + m * 16 + rl) * 32 + kqs];
#pragma unroll
    for (int n = 0; n < 4; ++n) bfr[n] = *(const bf16x8*)&Bc[(wc + n * 16 + rl) * 32 + kqs];
#pragma unroll
    for (int m = 0; m < 4; ++m)
#pragma unroll
      for (int n = 0; n < 4; ++n) acc[m][n] = MFMA_BF16(af[m], bfr[n], acc[m][n]);

    if (kt + 2 < NT) {
      const int nb = buf + 2 >= 3 ? buf - 1 : buf + 2;
      STAGE(kt + 2, nb);
    }
    if (kt + 1 < NT) {
      if (kt + 2 < NT) asm volatile("s_waitcnt vmcnt(4)" ::: "memory");
      else             asm volatile("s_waitcnt vmcnt(0)" ::: "memory");
      __builtin_amdgcn_s_barrier();
      __builtin_amdgcn_sched_barrier(0);
    }
    buf = buf == 2 ? 0 : buf + 1;
  }
#undef STAGE

  // ---------------- epilogue ----------------
  if constexpr (OUT == 3) {
#pragma unroll
    for (int n = 0; n < 4; ++n) {
      const int gcol = tN * 128 + wc + n * 16 + rl;
      const float bia = bias0[gcol];
#pragma unroll
      for (int m = 0; m < 4; ++m) {
#pragma unroll
        for (int i = 0; i < 4; ++i) {
          const long grow = (long)tM * 128 + wr + m * 16 + g * 4 + i;
          if (grow < M) ((float*)Y0)[grow * DIM + gcol] = acc[m][n][i] + bia;
        }
      }
    }
    return;
  }

  constexpr int TP = 136;  // padded stride for the 128x128 bf16 staging tile
  bf16* smT = sm;          // 128*136*2 = 34.8 KB < 48 KB
  __syncthreads();         // all compute done; sm safe to reuse

  const bool vpath = (OUT == 1) && (tN >= 6);
  if (vpath) {
    // store transposed: smT[col*TP + row] so writeback is contiguous along l
#pragma unroll
    for (int n = 0; n < 4; ++n) {
      const int col = wc + n * 16 + rl;
      const float bia = bias1[tN * 128 + col - 768];
#pragma unroll
      for (int m = 0; m < 4; ++m) {
        const int row = wr + m * 16 + g * 4;
        bf16x4 v4;
#pragma unroll
        for (int i = 0; i < 4; ++i) v4[i] = (bf16)(acc[m][n][i] + bia);
        *(bf16x4*)(smT + col * TP + row) = v4;
      }
    }
    __syncthreads();
    bf16* vout = (bf16*)Y1;
    const int tNv = tN - 6;
#pragma unroll
    for (int it = 0; it < 8; ++it) {
      const int c = it * 256 + tid;
      const int coll = c >> 4;
      const int rw0 = (c & 15) * 8;
      const long g2 = (long)tM * 128 + rw0;
      if (g2 < M) {
        const int b2 = (int)(g2 / L);
        const int l2 = (int)(g2 - (long)b2 * L);
        const int cv = tNv * 128 + coll;
        bf16* dst = vout + (((size_t)b2 * NH + (cv >> 6)) * 64 + (cv & 63)) * Lv;
        const bf16x8 v = *(const bf16x8*)(smT + coll * TP + rw0);
        if (l2 + 8 <= L) {
          *(bf16x8*)(dst + l2) = v;
        } else {  // chunk crosses a batch boundary
#pragma unroll
          for (int j = 0; j < 8; ++j) {
            const long g3 = g2 + j;
            const int b3 = (int)(g3 / L), l3 = (int)(g3 - (long)b3 * L);
            vout[(((size_t)b3 * NH + (cv >> 6)) * 64 + (cv & 63)) * Lv + l3] = v[j];
          }
        }
      }
    }
  } else {
    // Q / K: smT[row*TP + col], writeback contiguous along col
    const float scale = (OUT == 0) ? 0.125f : 1.f;
#pragma unroll
    for (int n = 0; n < 4; ++n) {
      const int col = wc + n * 16 + rl;
      const float bia = bias0[tN * 128 + col];
#pragma unroll
      for (int m = 0; m < 4; ++m) {
#pragma unroll
        for (int i = 0; i < 4; ++i) {
          const int row = wr + m * 16 + g * 4 + i;
          smT[row * TP + col] = (bf16)((acc[m][n][i] + bia) * scale);
        }
      }
    }
    __syncthreads();
    bf16* kout = (bf16*)Y0;
#pragma unroll
    for (int it = 0; it < 8; ++it) {
      const int c = it * 256 + tid;
      const int row = c >> 4;
      const int col0 = (c & 15) * 8;
      const long g2 = (long)tM * 128 + row;
      if (g2 < M) {
        const int b2 = (int)(g2 / L);
        const int l2 = (int)(g2 - (long)b2 * L);
        const int gc = tN * 128 + col0;
        const bf16x8 v = *(const bf16x8*)(smT + row * TP + col0);
        int dchunk = (gc & 63) >> 3;
        if constexpr (OUT == 1) dchunk ^= (l2 & 7);  // pre-swizzle K's global layout
        *(bf16x8*)(kout + (((size_t)b2 * NH + (gc >> 6)) * L + l2) * 64 + dchunk * 8) = v;
      }
    }
  }
}

// ---------------- fused attention: one block per (b,h), loops over 5 q-tiles ----------------
// K staged ONCE per bh via global_load_lds, consumed by all 5 q-tiles (r18: validated,
// attn left top-5). Ks read-only after the single barrier; Ps rows wave-private.
// Max-free single-pass softmax; V from global with 2-deep ring.
template <int L, int BRANCH>
__global__ __launch_bounds__(256, 2) void attn_kernel(
    const bf16* __restrict__ qb, const bf16* __restrict__ kb, const bf16* __restrict__ vb,
    float* __restrict__ ctx, bf16* __restrict__ xbuf, int Lv) {
  constexpr int LK16 = (L + 15) & ~15;
  constexpr int NKT = LK16 / 16;
  constexpr int LP32 = (L + 31) & ~31;
  constexpr int NK32 = LP32 / 32;
  constexpr int PSTR = LP32 + 8;
  __shared__ alignas(16) bf16 Ks[LK16 * 64];  // swizzled rows (as stored in global)
  __shared__ alignas(16) bf16 Ps[64 * PSTR];

  const int tid = threadIdx.x, lane = tid & 63, w = tid >> 6;
  // XCD swizzle: gridDim.x = 768 = 8*96
  const int orig = blockIdx.x;
  const int nper = gridDim.x >> 3;
  const int bh = (orig & 7) * nper + (orig >> 3);
  const int b = bh / NH, h = bh % NH;
  const int cl = lane & 15, g = lane >> 4;

  // ---- DMA-stage K once: linear copy (global pre-swizzled); tail rows garbage ----
  const bf16* kbase = kb + (size_t)bh * L * 64;
  for (int c = tid; c < LK16 * 8; c += 256)
    gload_lds16(kbase + (size_t)c * 8, Ks + (size_t)c * 8);
  __syncthreads();  // drains K-DMA + visibility for all waves

  const bf16* vbase = vb + (size_t)bh * 64 * Lv;

  for (int qt = 0; qt < 5; ++qt) {
    int sq = qt * 64 + w * 16 + cl;
    if (sq > 256) sq = 256;
    const bf16* qrow = qb + ((size_t)bh * 257 + sq) * 64 + g * 8;
    const bf16x8 aq0 = *(const bf16x8*)qrow;
    const bf16x8 aq1 = *(const bf16x8*)(qrow + 32);

    // ---- fused QK^T + exp + P-store (scale folded into Q) ----
    float sums[4] = {0.f, 0.f, 0.f, 0.f};
    const int prow0 = (w * 16 + g * 4) * PSTR + cl;  // row q = w*16+g*4+j
#pragma unroll
    for (int kt = 0; kt < NKT; ++kt) {
      const int key0 = kt * 16 + cl;
      const int sw = key0 & 7;
      const char* krow = (const char*)Ks + key0 * 128;
      const bf16x8 bk0 = *(const bf16x8*)(krow + ((g ^ sw) << 4));
      const bf16x8 bk1 = *(const bf16x8*)(krow + (((4 + g) ^ sw) << 4));
      f32x4 z = {0.f, 0.f, 0.f, 0.f};
      z = MFMA_BF16(aq0, bk0, z);
      z = MFMA_BF16(aq1, bk1, z);
      const bool valid = key0 < L;
#pragma unroll
      for (int j = 0; j < 4; ++j) {
        const float p = valid ? __expf(z[j]) : 0.f;  // |s| small: max-free softmax
        sums[j] += p;
        Ps[prow0 + j * PSTR + kt * 16] = (bf16)p;
      }
    }
    if constexpr (LP32 > LK16) {
#pragma unroll
      for (int j = 0; j < 4; ++j) Ps[prow0 + j * PSTR + LK16] = (bf16)0.f;
    }

    // ---- T14: first V-group issued before the sum reduction ----
    bf16x8 vr0[4], vr1[4];
#pragma unroll
    for (int nt = 0; nt < 4; ++nt)
      vr0[nt] = *(const bf16x8*)(vbase + (size_t)(nt * 16 + cl) * Lv + g * 8);

#pragma unroll
    for (int j = 0; j < 4; ++j) {
      sums[j] += __shfl_xor(sums[j], 1);
      sums[j] += __shfl_xor(sums[j], 2);
      sums[j] += __shfl_xor(sums[j], 4);
      sums[j] += __shfl_xor(sums[j], 8);
    }
    float inv[4];
#pragma unroll
    for (int j = 0; j < 4; ++j) inv[j] = 1.f / sums[j];
    // no barrier: each wave reads only its own 16 Ps rows (same-wave DS ordering)

    // ---- PV with 2-deep V ring; normalization applied at the store ----
    f32x4 cacc[4];
#pragma unroll
    for (int nt = 0; nt < 4; ++nt) cacc[nt] = f32x4{0.f, 0.f, 0.f, 0.f};
#pragma unroll
    for (int kt = 0; kt < NK32; ++kt) {
      const bool even = (kt & 1) == 0;
      if (kt + 1 < NK32) {
        int kk = (kt + 1) * 32 + g * 8;
        if (kk > Lv - 8) kk = Lv - 8;  // clamp: only P==0 keys affected
#pragma unroll
        for (int nt = 0; nt < 4; ++nt) {
          const bf16x8 v = *(const bf16x8*)(vbase + (size_t)(nt * 16 + cl) * Lv + kk);
          if (even) vr1[nt] = v; else vr0[nt] = v;
        }
      }
      const bf16x8 ap = *(const bf16x8*)&Ps[(w * 16 + cl) * PSTR + kt * 32 + g * 8];
#pragma unroll
      for (int nt = 0; nt < 4; ++nt)
        cacc[nt] = MFMA_BF16(ap, even ? vr0[nt] : vr1[nt], cacc[nt]);
    }

#pragma unroll
    for (int nt = 0; nt < 4; ++nt) {
#pragma unroll
      for (int i = 0; i < 4; ++i) {
        const int s_q = qt * 64 + w * 16 + g * 4 + i;
        if (s_q < 257) {
          const size_t idx = ((size_t)b * 257 + s_q) * DIM + h * 64 + nt * 16 + cl;
          const float val = cacc[nt][i] * inv[i];
          if constexpr (BRANCH == 0)
            ctx[idx] = val;
          else if constexpr (BRANCH == 1)
            ctx[idx] += val;
          else
            xbuf[idx] = (bf16)((ctx[idx] + val) * (1.f / 3.f));
        }
      }
    }
  }
}

extern "C" void kernel_launch(void* const* d_in, const int* in_sizes, int n_in,
                              void* d_out, int out_size, void* d_ws, size_t ws_size,
                              hipStream_t stream) {
  (void)in_sizes; (void)n_in; (void)out_size; (void)ws_size;
  const float* hs = (const float*)d_in[0];
  const float* Wq = (const float*)d_in[1];
  const float* bq = (const float*)d_in[2];
  const float* Wk = (const float*)d_in[3];
  const float* bk = (const float*)d_in[4];
  const float* Wv = (const float*)d_in[5];
  const float* bv = (const float*)d_in[6];
  const float* Wo = (const float*)d_in[7];
  const float* bo = (const float*)d_in[8];
  const float* c1 = (const float*)d_in[9];
  const float* c2 = (const float*)d_in[10];
  const float* c3 = (const float*)d_in[11];
  float* out = (float*)d_out;

  constexpr size_t QB = (size_t)BATCH * NH * SEQ * 64;
  constexpr size_t XB = (size_t)BATCH * SEQ * DIM;
  constexpr size_t K1 = (size_t)BATCH * NH * 257 * 64;

  bf16* wbf = (bf16*)d_ws;                          // [Wq|Wk|Wv|Wo] bf16
  bf16* qb = wbf + 4 * WE;                          // [B][H][257][64]
  bf16* xb = qb + QB;                               // [B][Lmax][768]; aliases hsb before conv1
  bf16* kbf = xb + XB;                              // [B][H][L][64], chunk-swizzled
  bf16* vbf = kbf + K1;                             // [B][H][64][Lv<=264]
  bf16* hsb = xb;

  cvt_weights<<<dim3((unsigned)((4 * WE / 4 + 255) / 256)), 256, 0, stream>>>(Wq, Wk, Wv, Wo, wbf);
  cvt_hs<<<dim3((BATCH * SEQ * DIM / 4 + 255) / 256), 256, 0, stream>>>(hs, hsb, BATCH * SEQ * DIM / 4);

  // Q projection (scale 1/8 folded), from bf16 hs
  gemm_lds_kernel<0><<<dim3(129 * 6), 256, 0, stream>>>(hsb, wbf, bq, bq, qb, qb, BATCH * SEQ, 257, 1, 6);

  // ---- branch 0: 1x1 conv, L=257 ----
  conv_kernel<1><<<dim3(24, 64), 256, 0, stream>>>(hs, c1, xb);
  gemm_lds_kernel<1><<<dim3(129 * 12), 256, 0, stream>>>(xb, wbf + WE, bk, bv, kbf, vbf, BATCH * 257, 257, 264, 12);
  attn_kernel<257, 0><<<dim3(768), 256, 0, stream>>>(qb, kbf, vbf, out, xb, 264);

  // ---- branch 1: 3x3 conv, L=197 ----
  conv_kernel<3><<<dim3(24, 64), 256, 0, stream>>>(hs, c2, xb);
  gemm_lds_kernel<1><<<dim3(99 * 12), 256, 0, stream>>>(xb, wbf + WE, bk, bv, kbf, vbf, BATCH * 197, 197, 200, 12);
  attn_kernel<197, 1><<<dim3(768), 256, 0, stream>>>(qb, kbf, vbf, out, xb, 200);

  // ---- branch 2: 5x5 conv, L=145 ----
  conv_kernel<5><<<dim3(24, 64), 256, 0, stream>>>(hs, c3, xb);
  gemm_lds_kernel<1><<<dim3(73 * 12), 256, 0, stream>>>(xb, wbf + WE, bk, bv, kbf, vbf, BATCH * 145, 145, 152, 12);
  attn_kernel<145, 2><<<dim3(768), 256, 0, stream>>>(qb, kbf, vbf, out, xb, 152);

  // ---- output projection: out = bf16(ctx/3) @ Wo^T + bo ----
  gemm_lds_kernel<3><<<dim3(129 * 6), 256, 0, stream>>>(xb, wbf + 3 * WE, bo, bo, out, out, BATCH * SEQ, 257, 1, 6);
}

// Round 20
// 514.645 us; speedup vs baseline: 1.1186x; 1.0250x over previous
//
#include <hip/hip_runtime.h>

using bf16   = __bf16;
using bf16x4 = __bf16 __attribute__((ext_vector_type(4)));
using bf16x8 = __bf16 __attribute__((ext_vector_type(8)));
using f32x4  = float __attribute__((ext_vector_type(4)));

#define MFMA_BF16(a, b, c) __builtin_amdgcn_mfma_f32_16x16x32_bf16((a), (b), (c), 0, 0, 0)

constexpr int BATCH = 64, SEQ = 257, DIM = 768, NH = 12;
constexpr size_t WE = (size_t)DIM * DIM;

__device__ inline void gload_lds16(const bf16* g, bf16* l) {
  __builtin_amdgcn_global_load_lds(
      (const __attribute__((address_space(1))) void*)g,
      (__attribute__((address_space(3))) void*)l, 16, 0, 0);
}

// ---------------- weights fp32 -> bf16, order [Wq | Wk*c1 | Wv*c1 | Wk | Wv | Wo] ----------------
__global__ __launch_bounds__(256) void cvt_weights6(
    const float* __restrict__ wq, const float* __restrict__ wk,
    const float* __restrict__ wv, const float* __restrict__ wo,
    const float* __restrict__ c1, bf16* __restrict__ dst) {
  const size_t i = (size_t)blockIdx.x * 256 + threadIdx.x;  // float4 index
  const size_t per = WE / 4;
  if (i >= 6 * per) return;
  const int region = (int)(i / per);
  const size_t within = i % per;
  const float* srcs[6] = {wq, wk, wv, wk, wv, wo};
  const float4 f = ((const float4*)srcs[region])[within];
  float v[4] = {f.x, f.y, f.z, f.w};
  if (region == 1 || region == 2) {
    const int c0 = (int)((within * 4) % DIM);
#pragma unroll
    for (int j = 0; j < 4; ++j) v[j] *= c1[c0 + j];
  }
  bf16* o = dst + i * 4;
#pragma unroll
  for (int j = 0; j < 4; ++j) o[j] = (bf16)v[j];
}

// ---------------- hs fp32 -> bf16 ----------------
__global__ __launch_bounds__(256) void cvt_hs(const float* __restrict__ src,
                                              bf16* __restrict__ dst, int n4) {
  const int i = blockIdx.x * 256 + threadIdx.x;
  if (i >= n4) return;
  const float4 f = ((const float4*)src)[i];
  bf16* o = dst + (size_t)i * 4;
  o[0] = (bf16)f.x; o[1] = (bf16)f.y; o[2] = (bf16)f.z; o[3] = (bf16)f.w;
}

// ---------------- depthwise conv + cls concat -> xb bf16 [B][L][768] ----------------
template <int KS>
__global__ __launch_bounds__(256) void conv_kernel(
    const float* __restrict__ hs, const float* __restrict__ cw, bf16* __restrict__ xb) {
  constexpr int OW = 17 - KS;
  constexpr int NOUT = OW * OW;
  constexpr int L = NOUT + 1;
  constexpr int KSQ = KS * KS;
  constexpr int NP = (NOUT + 7) / 8;
  __shared__ float hsl[256][36];
  __shared__ float wsm[32][KSQ];

  const int t = threadIdx.x;
  const int b = blockIdx.y;
  const int c0 = blockIdx.x * 32;

  const float* src = hs + ((size_t)b * SEQ + 1 + t) * DIM + c0;
#pragma unroll
  for (int j = 0; j < 8; ++j) *(float4*)&hsl[t][4 * j] = ((const float4*)src)[j];

  if (t < 32) {
#pragma unroll
    for (int q = 0; q < KSQ; ++q) wsm[t][q] = cw[(size_t)(c0 + t) * KSQ + q];
    const float cv = hs[(size_t)b * SEQ * DIM + c0 + t];
    xb[(size_t)b * L * DIM + c0 + t] = (bf16)cv;
  }
  __syncthreads();

  const int c = t & 31, pg = t >> 5;
#pragma unroll
  for (int i = 0; i < NP; ++i) {
    const int p = pg * NP + i;
    if (p < NOUT) {
      const int oi = p / OW, oj = p - oi * OW;
      float a = 0.f;
#pragma unroll
      for (int di = 0; di < KS; ++di)
#pragma unroll
        for (int dj = 0; dj < KS; ++dj)
          a += hsl[(oi + di) * 16 + oj + dj][c] * wsm[c][di * KS + dj];
      xb[((size_t)b * L + 1 + p) * DIM + c0 + c] = (bf16)a;
    }
  }
}

// ---------------- GEMM core (r19-measured body: 3 buffers, counted vmcnt(4), ----------------
// both-sides chunk swizzle, LDS-staged epilogue). OUT: 1 = KV (N=1536, Y0=K,Y1=V);
// 3 = fp32 out [M][768] (Y0); 4 = QKV (N=2304, Y0=Q x0.125, Y1=K swz, Y2=V transposed).
template <int OUT>
__device__ __forceinline__ void gemm_core(
    bf16* sm, const bf16* A, const bf16* W,
    const float* b0, const float* b1, const float* b2,
    void* Y0, void* Y1, void* Y2, int M, int L, int Lv, int tM, int tN, int tid) {
  constexpr int BUF_E = 128 * 32;
  bf16* smA = sm;
  bf16* smB = sm + 3 * BUF_E;

  const int lane = tid & 63;
  const int w = tid >> 6;
  const int wr = (w >> 1) * 64, wc = (w & 1) * 64;
  const int rl = lane & 15;
  const int g = lane >> 4;
  const int kqs = ((g ^ ((rl >> 1) & 3)) << 3);  // read-side chunk deswizzle

  const int sr = lane >> 2;
  const int sk = (((lane & 3) ^ ((sr >> 1) & 3)) << 3);  // staging global pre-swizzle
  const int r0 = w * 32 + sr;
  const int r1 = w * 32 + 16 + sr;
  long ga0 = (long)tM * 128 + r0; if (ga0 >= M) ga0 = M - 1;
  long ga1 = (long)tM * 128 + r1; if (ga1 >= M) ga1 = M - 1;
  const bf16* pa0 = A + ga0 * DIM + sk;
  const bf16* pa1 = A + ga1 * DIM + sk;
  const bf16* pb0 = W + ((size_t)tN * 128 + r0) * DIM + sk;
  const bf16* pb1 = W + ((size_t)tN * 128 + r1) * DIM + sk;
  const int lbase = (w * 32) * 32;

  const f32x4 zero4 = {0.f, 0.f, 0.f, 0.f};
  f32x4 acc[4][4];
#pragma unroll
  for (int m = 0; m < 4; ++m)
#pragma unroll
    for (int n = 0; n < 4; ++n) acc[m][n] = zero4;

  constexpr int NT = DIM / 32;  // 24 K-steps

#define STAGE(kt_, buf_)                                      \
  do {                                                        \
    const int kb_ = (kt_) * 32;                               \
    bf16* a_ = smA + (buf_) * BUF_E + lbase;                  \
    bf16* b_ = smB + (buf_) * BUF_E + lbase;                  \
    gload_lds16(pa0 + kb_, a_);                               \
    gload_lds16(pa1 + kb_, a_ + 512);                         \
    gload_lds16(pb0 + kb_, b_);                               \
    gload_lds16(pb1 + kb_, b_ + 512);                         \
  } while (0)

  STAGE(0, 0);
  STAGE(1, 1);
  asm volatile("s_waitcnt vmcnt(4)" ::: "memory");
  __builtin_amdgcn_s_barrier();
  __builtin_amdgcn_sched_barrier(0);

  int buf = 0;
  for (int kt = 0; kt < NT; ++kt) {
    const bf16* Ac = smA + buf * BUF_E;
    const bf16* Bc = smB + buf * BUF_E;
    bf16x8 af[4], bfr[4];
#pragma unroll
    for (int m = 0; m < 4; ++m) af[m] = *(const bf16x8*)&Ac[(wr + m * 16 + rl) * 32 + kqs];
#pragma unroll
    for (int n = 0; n < 4; ++n) bfr[n] = *(const bf16x8*)&Bc[(wc + n * 16 + rl) * 32 + kqs];
#pragma unroll
    for (int m = 0; m < 4; ++m)
#pragma unroll
      for (int n = 0; n < 4; ++n) acc[m][n] = MFMA_BF16(af[m], bfr[n], acc[m][n]);

    if (kt + 2 < NT) {
      const int nb = buf + 2 >= 3 ? buf - 1 : buf + 2;
      STAGE(kt + 2, nb);
    }
    if (kt + 1 < NT) {
      if (kt + 2 < NT) asm volatile("s_waitcnt vmcnt(4)" ::: "memory");
      else             asm volatile("s_waitcnt vmcnt(0)" ::: "memory");
      __builtin_amdgcn_s_barrier();
      __builtin_amdgcn_sched_barrier(0);
    }
    buf = buf == 2 ? 0 : buf + 1;
  }
#undef STAGE

  // ---------------- epilogue ----------------
  if constexpr (OUT == 3) {
#pragma unroll
    for (int n = 0; n < 4; ++n) {
      const int gcol = tN * 128 + wc + n * 16 + rl;
      const float bia = b0[gcol];
#pragma unroll
      for (int m = 0; m < 4; ++m) {
#pragma unroll
        for (int i = 0; i < 4; ++i) {
          const long grow = (long)tM * 128 + wr + m * 16 + g * 4 + i;
          if (grow < M) ((float*)Y0)[grow * DIM + gcol] = acc[m][n][i] + bia;
        }
      }
    }
    return;
  }

  constexpr int TP = 136;
  bf16* smT = sm;
  __syncthreads();  // all compute + DMA done; sm reusable

  const bool vpath = (OUT == 1 && tN >= 6) || (OUT == 4 && tN >= 12);
  const bool qpath = (OUT == 4 && tN < 6);

  if (vpath) {
    const int cbase = (OUT == 4) ? 1536 : 768;
    const float* bv_ = (OUT == 4) ? b2 : b1;
#pragma unroll
    for (int n = 0; n < 4; ++n) {
      const int col = wc + n * 16 + rl;
      const float bia = bv_[tN * 128 + col - cbase];
#pragma unroll
      for (int m = 0; m < 4; ++m) {
        const int row = wr + m * 16 + g * 4;
        bf16x4 v4;
#pragma unroll
        for (int i = 0; i < 4; ++i) v4[i] = (bf16)(acc[m][n][i] + bia);
        *(bf16x4*)(smT + col * TP + row) = v4;
      }
    }
    __syncthreads();
    bf16* vout = (bf16*)((OUT == 4) ? Y2 : Y1);
    const int tNv = tN - ((OUT == 4) ? 12 : 6);
#pragma unroll
    for (int it = 0; it < 8; ++it) {
      const int c = it * 256 + tid;
      const int coll = c >> 4;
      const int rw0 = (c & 15) * 8;
      const long g2 = (long)tM * 128 + rw0;
      if (g2 < M) {
        const int b2i = (int)(g2 / L);
        const int l2 = (int)(g2 - (long)b2i * L);
        const int cv = tNv * 128 + coll;
        bf16* dst = vout + (((size_t)b2i * NH + (cv >> 6)) * 64 + (cv & 63)) * Lv;
        const bf16x8 v = *(const bf16x8*)(smT + coll * TP + rw0);
        if (l2 + 8 <= L) {
          *(bf16x8*)(dst + l2) = v;
        } else {
#pragma unroll
          for (int j = 0; j < 8; ++j) {
            const long g3 = g2 + j;
            const int b3 = (int)(g3 / L), l3 = (int)(g3 - (long)b3 * L);
            vout[(((size_t)b3 * NH + (cv >> 6)) * 64 + (cv & 63)) * Lv + l3] = v[j];
          }
        }
      }
    }
  } else {
    // Q (OUT==4, tN<6) or K (OUT==1 tN<6 / OUT==4 6<=tN<12)
    const float scale = qpath ? 0.125f : 1.f;
#pragma unroll
    for (int n = 0; n < 4; ++n) {
      const int col = wc + n * 16 + rl;
      const int gcol = tN * 128 + col;
      float bia;
      if constexpr (OUT == 4) bia = (gcol < 768) ? b0[gcol] : b1[gcol - 768];
      else                    bia = b0[gcol];
#pragma unroll
      for (int m = 0; m < 4; ++m) {
#pragma unroll
        for (int i = 0; i < 4; ++i) {
          const int row = wr + m * 16 + g * 4 + i;
          smT[row * TP + col] = (bf16)((acc[m][n][i] + bia) * scale);
        }
      }
    }
    __syncthreads();
    bf16* kout = (bf16*)((OUT == 4 && !qpath) ? Y1 : Y0);
    const int coff = (OUT == 4 && !qpath) ? 768 : 0;
    const bool kswz = !qpath;  // K outputs chunk-swizzled for attn's linear DMA
#pragma unroll
    for (int it = 0; it < 8; ++it) {
      const int c = it * 256 + tid;
      const int row = c >> 4;
      const int col0 = (c & 15) * 8;
      const long g2 = (long)tM * 128 + row;
      if (g2 < M) {
        const int b2i = (int)(g2 / L);
        const int l2 = (int)(g2 - (long)b2i * L);
        const int gc = tN * 128 + col0 - coff;
        const bf16x8 v = *(const bf16x8*)(smT + row * TP + col0);
        int dchunk = (gc & 63) >> 3;
        if (kswz) dchunk ^= (l2 & 7);
        *(bf16x8*)(kout + (((size_t)b2i * NH + (gc >> 6)) * L + l2) * 64 + dchunk * 8) = v;
      }
    }
  }
}

__device__ __forceinline__ int m204_swz(int orig, int nwg) {
  const int nq = nwg >> 3, rr = nwg & 7, xcd = orig & 7, base = orig >> 3;
  return (xcd < rr ? xcd * (nq + 1) : rr * (nq + 1) + (xcd - rr) * nq) + base;
}

// ---- QKV0 mega-GEMM: A=hs_bf16, W=[Wq|Wk*c1|Wv*c1], N=2304, nN=18 ----
__global__ __launch_bounds__(256, 4) void gemm_qkv0_kernel(
    const bf16* __restrict__ A, const bf16* __restrict__ W,
    const float* __restrict__ bq, const float* __restrict__ bk, const float* __restrict__ bv,
    bf16* __restrict__ qb, bf16* __restrict__ kb, bf16* __restrict__ vb) {
  constexpr int BUF_E = 128 * 32;
  __shared__ alignas(16) bf16 sm[6 * BUF_E];
  const int wgid = m204_swz(blockIdx.x, gridDim.x);
  const int tM = wgid / 18, tN = wgid - tM * 18;
  gemm_core<4>(sm, A, W, bq, bk, bv, qb, kb, vb, BATCH * SEQ, 257, 264, tM, tN, threadIdx.x);
}

// ---- fused KV1+KV2 GEMM: range [0,1188) branch1, [1188,2064) branch2 ----
__global__ __launch_bounds__(256, 4) void gemm_kv12_kernel(
    const bf16* __restrict__ A1, const bf16* __restrict__ A2, const bf16* __restrict__ W,
    const float* __restrict__ bk, const float* __restrict__ bv,
    bf16* __restrict__ k1, bf16* __restrict__ v1,
    bf16* __restrict__ k2, bf16* __restrict__ v2) {
  constexpr int BUF_E = 128 * 32;
  __shared__ alignas(16) bf16 sm[6 * BUF_E];
  const int wgid = m204_swz(blockIdx.x, gridDim.x);
  if (wgid < 1188) {
    const int tM = wgid / 12, tN = wgid - tM * 12;
    gemm_core<1>(sm, A1, W, bk, bv, nullptr, k1, v1, nullptr, BATCH * 197, 197, 200, tM, tN, threadIdx.x);
  } else {
    const int l = wgid - 1188;
    const int tM = l / 12, tN = l - tM * 12;
    gemm_core<1>(sm, A2, W, bk, bv, nullptr, k2, v2, nullptr, BATCH * 145, 145, 152, tM, tN, threadIdx.x);
  }
}

// ---- O projection ----
__global__ __launch_bounds__(256, 4) void gemm_o_kernel(
    const bf16* __restrict__ A, const bf16* __restrict__ W,
    const float* __restrict__ bo, float* __restrict__ out) {
  constexpr int BUF_E = 128 * 32;
  __shared__ alignas(16) bf16 sm[6 * BUF_E];
  const int wgid = m204_swz(blockIdx.x, gridDim.x);
  const int tM = wgid / 6, tN = wgid - tM * 6;
  gemm_core<3>(sm, A, W, bo, nullptr, nullptr, out, nullptr, nullptr, BATCH * SEQ, 257, 1, tM, tN, threadIdx.x);
}

// ---- cls fixup: branch-0 K/V row l=0 must use UNSCALED Wk/Wv ----
// grid (12, 64): x<6 -> K cols, x>=6 -> V cols; 128 cols per block, dot-768 each.
__global__ __launch_bounds__(256) void cls_fixup_kernel(
    const bf16* __restrict__ hsb, const bf16* __restrict__ wk, const bf16* __restrict__ wv,
    const float* __restrict__ bk, const float* __restrict__ bv,
    bf16* __restrict__ k12, bf16* __restrict__ v12) {
  __shared__ float hrow[DIM];
  const int b = blockIdx.y, tile = blockIdx.x, t = threadIdx.x;
  for (int i = t; i < DIM; i += 256) hrow[i] = (float)hsb[(size_t)b * SEQ * DIM + i];
  __syncthreads();
  const bool isv = tile >= 6;
  const int o = (tile - (isv ? 6 : 0)) * 128 + (t >> 1);  // output col in [0,768)
  const int half = t & 1;
  const bf16* wrow = (isv ? wv : wk) + (size_t)o * DIM + half * 384;
  float s = 0.f;
#pragma unroll 4
  for (int k = 0; k < 48; ++k) {
    const bf16x8 wv8 = *(const bf16x8*)(wrow + k * 8);
#pragma unroll
    for (int j = 0; j < 8; ++j) s += hrow[half * 384 + k * 8 + j] * (float)wv8[j];
  }
  s += __shfl_xor(s, 1);
  if (!half) {
    s += (isv ? bv : bk)[o];
    if (!isv) {
      // K[b][h][0][col]; l=0 -> chunk swizzle identity
      k12[(((size_t)b * NH + (o >> 6)) * 257) * 64 + (o & 63)] = (bf16)s;
    } else {
      v12[(((size_t)b * NH + (o >> 6)) * 64 + (o & 63)) * 264] = (bf16)s;
    }
  }
}

// ---------------- fused attention: one block per (b,h), loops over 5 q-tiles ----------------
template <int L, int BRANCH>
__global__ __launch_bounds__(256, 2) void attn_kernel(
    const bf16* __restrict__ qb, const bf16* __restrict__ kb, const bf16* __restrict__ vb,
    float* __restrict__ ctx, bf16* __restrict__ xbuf, int Lv) {
  constexpr int LK16 = (L + 15) & ~15;
  constexpr int NKT = LK16 / 16;
  constexpr int LP32 = (L + 31) & ~31;
  constexpr int NK32 = LP32 / 32;
  constexpr int PSTR = LP32 + 8;
  __shared__ alignas(16) bf16 Ks[LK16 * 64];
  __shared__ alignas(16) bf16 Ps[64 * PSTR];

  const int tid = threadIdx.x, lane = tid & 63, w = tid >> 6;
  const int orig = blockIdx.x;
  const int nper = gridDim.x >> 3;
  const int bh = (orig & 7) * nper + (orig >> 3);
  const int b = bh / NH, h = bh % NH;
  const int cl = lane & 15, g = lane >> 4;

  const bf16* kbase = kb + (size_t)bh * L * 64;
  for (int c = tid; c < LK16 * 8; c += 256)
    gload_lds16(kbase + (size_t)c * 8, Ks + (size_t)c * 8);
  __syncthreads();

  const bf16* vbase = vb + (size_t)bh * 64 * Lv;

  for (int qt = 0; qt < 5; ++qt) {
    int sq = qt * 64 + w * 16 + cl;
    if (sq > 256) sq = 256;
    const bf16* qrow = qb + ((size_t)bh * 257 + sq) * 64 + g * 8;
    const bf16x8 aq0 = *(const bf16x8*)qrow;
    const bf16x8 aq1 = *(const bf16x8*)(qrow + 32);

    float sums[4] = {0.f, 0.f, 0.f, 0.f};
    const int prow0 = (w * 16 + g * 4) * PSTR + cl;
#pragma unroll
    for (int kt = 0; kt < NKT; ++kt) {
      const int key0 = kt * 16 + cl;
      const int sw = key0 & 7;
      const char* krow = (const char*)Ks + key0 * 128;
      const bf16x8 bk0 = *(const bf16x8*)(krow + ((g ^ sw) << 4));
      const bf16x8 bk1 = *(const bf16x8*)(krow + (((4 + g) ^ sw) << 4));
      f32x4 z = {0.f, 0.f, 0.f, 0.f};
      z = MFMA_BF16(aq0, bk0, z);
      z = MFMA_BF16(aq1, bk1, z);
      const bool valid = key0 < L;
#pragma unroll
      for (int j = 0; j < 4; ++j) {
        const float p = valid ? __expf(z[j]) : 0.f;
        sums[j] += p;
        Ps[prow0 + j * PSTR + kt * 16] = (bf16)p;
      }
    }
    if constexpr (LP32 > LK16) {
#pragma unroll
      for (int j = 0; j < 4; ++j) Ps[prow0 + j * PSTR + LK16] = (bf16)0.f;
    }

    bf16x8 vr0[4], vr1[4];
#pragma unroll
    for (int nt = 0; nt < 4; ++nt)
      vr0[nt] = *(const bf16x8*)(vbase + (size_t)(nt * 16 + cl) * Lv + g * 8);

#pragma unroll
    for (int j = 0; j < 4; ++j) {
      sums[j] += __shfl_xor(sums[j], 1);
      sums[j] += __shfl_xor(sums[j], 2);
      sums[j] += __shfl_xor(sums[j], 4);
      sums[j] += __shfl_xor(sums[j], 8);
    }
    float inv[4];
#pragma unroll
    for (int j = 0; j < 4; ++j) inv[j] = 1.f / sums[j];

    f32x4 cacc[4];
#pragma unroll
    for (int nt = 0; nt < 4; ++nt) cacc[nt] = f32x4{0.f, 0.f, 0.f, 0.f};
#pragma unroll
    for (int kt = 0; kt < NK32; ++kt) {
      const bool even = (kt & 1) == 0;
      if (kt + 1 < NK32) {
        int kk = (kt + 1) * 32 + g * 8;
        if (kk > Lv - 8) kk = Lv - 8;
#pragma unroll
        for (int nt = 0; nt < 4; ++nt) {
          const bf16x8 v = *(const bf16x8*)(vbase + (size_t)(nt * 16 + cl) * Lv + kk);
          if (even) vr1[nt] = v; else vr0[nt] = v;
        }
      }
      const bf16x8 ap = *(const bf16x8*)&Ps[(w * 16 + cl) * PSTR + kt * 32 + g * 8];
#pragma unroll
      for (int nt = 0; nt < 4; ++nt)
        cacc[nt] = MFMA_BF16(ap, even ? vr0[nt] : vr1[nt], cacc[nt]);
    }

#pragma unroll
    for (int nt = 0; nt < 4; ++nt) {
#pragma unroll
      for (int i = 0; i < 4; ++i) {
        const int s_q = qt * 64 + w * 16 + g * 4 + i;
        if (s_q < 257) {
          const size_t idx = ((size_t)b * 257 + s_q) * DIM + h * 64 + nt * 16 + cl;
          const float val = cacc[nt][i] * inv[i];
          if constexpr (BRANCH == 0)
            ctx[idx] = val;
          else if constexpr (BRANCH == 1)
            ctx[idx] += val;
          else
            xbuf[idx] = (bf16)((ctx[idx] + val) * (1.f / 3.f));
        }
      }
    }
  }
}

extern "C" void kernel_launch(void* const* d_in, const int* in_sizes, int n_in,
                              void* d_out, int out_size, void* d_ws, size_t ws_size,
                              hipStream_t stream) {
  (void)in_sizes; (void)n_in; (void)out_size; (void)ws_size;
  const float* hs = (const float*)d_in[0];
  const float* Wq = (const float*)d_in[1];
  const float* bq = (const float*)d_in[2];
  const float* Wk = (const float*)d_in[3];
  const float* bk = (const float*)d_in[4];
  const float* Wv = (const float*)d_in[5];
  const float* bv = (const float*)d_in[6];
  const float* Wo = (const float*)d_in[7];
  const float* bo = (const float*)d_in[8];
  const float* c1 = (const float*)d_in[9];
  const float* c2 = (const float*)d_in[10];
  const float* c3 = (const float*)d_in[11];
  float* out = (float*)d_out;

  // layout (bf16 elems), total ~152.3 MB; ws proven >= 174.7 MB (r12 ran merged path)
  constexpr size_t QB = (size_t)BATCH * NH * SEQ * 64;       // 12,632,064
  constexpr size_t XB = (size_t)BATCH * SEQ * DIM;           // 12,632,064 (hsb -> xb2 slot)
  constexpr size_t K12 = (size_t)BATCH * NH * 257 * 64;      // k1 then reused as-is
  constexpr size_t V12 = (size_t)BATCH * NH * 64 * 264;
  constexpr size_t XB3 = (size_t)BATCH * 145 * DIM;
  constexpr size_t K3 = (size_t)BATCH * NH * 145 * 64;

  bf16* wbf = (bf16*)d_ws;           // [Wq|Wk*c1|Wv*c1|Wk|Wv|Wo] 6*WE
  bf16* qb  = wbf + 6 * WE;
  bf16* xb  = qb + QB;               // hsb, later conv2 output; finally ctx/3 bf16
  bf16* k12 = xb + XB;               // branch0 K, later branch1 K
  bf16* v12 = k12 + K12;             // branch0 V, later branch1 V
  bf16* xb3 = v12 + V12;             // conv3 output
  bf16* k3  = xb3 + XB3;
  bf16* v3  = k3 + K3;
  bf16* hsb = xb;

  cvt_weights6<<<dim3((unsigned)((6 * WE / 4 + 255) / 256)), 256, 0, stream>>>(Wq, Wk, Wv, Wo, c1, wbf);
  cvt_hs<<<dim3((BATCH * SEQ * DIM / 4 + 255) / 256), 256, 0, stream>>>(hs, hsb, BATCH * SEQ * DIM / 4);

  // ---- branch 0 (1x1 conv folded into weights): Q, K0, V0 in one GEMM + cls fixup ----
  gemm_qkv0_kernel<<<dim3(129 * 18), 256, 0, stream>>>(hsb, wbf, bq, bk, bv, qb, k12, v12);
  cls_fixup_kernel<<<dim3(12, 64), 256, 0, stream>>>(hsb, wbf + 3 * WE, wbf + 4 * WE, bk, bv, k12, v12);
  attn_kernel<257, 0><<<dim3(768), 256, 0, stream>>>(qb, k12, v12, out, xb, 264);

  // ---- branches 1 & 2: convs, fused KV GEMM, attns ----
  conv_kernel<3><<<dim3(24, 64), 256, 0, stream>>>(hs, c2, xb);    // xb free after attn0 (hsb done)
  conv_kernel<5><<<dim3(24, 64), 256, 0, stream>>>(hs, c3, xb3);
  gemm_kv12_kernel<<<dim3(1188 + 876), 256, 0, stream>>>(xb, xb3, wbf + 3 * WE, bk, bv,
                                                         k12, v12, k3, v3);
  attn_kernel<197, 1><<<dim3(768), 256, 0, stream>>>(qb, k12, v12, out, xb, 200);
  attn_kernel<145, 2><<<dim3(768), 256, 0, stream>>>(qb, k3, v3, out, xb, 152);

  // ---- output projection ----
  gemm_o_kernel<<<dim3(129 * 6), 256, 0, stream>>>(xb, wbf + 5 * WE, bo, out);
}

// Round 21
// 485.003 us; speedup vs baseline: 1.1870x; 1.0611x over previous
//
#include <hip/hip_runtime.h>

using bf16   = __bf16;
using bf16x4 = __bf16 __attribute__((ext_vector_type(4)));
using bf16x8 = __bf16 __attribute__((ext_vector_type(8)));
using f32x4  = float __attribute__((ext_vector_type(4)));

#define MFMA_BF16(a, b, c) __builtin_amdgcn_mfma_f32_16x16x32_bf16((a), (b), (c), 0, 0, 0)

constexpr int BATCH = 64, SEQ = 257, DIM = 768, NH = 12;
constexpr size_t WE = (size_t)DIM * DIM;

__device__ inline void gload_lds16(const bf16* g, bf16* l) {
  __builtin_amdgcn_global_load_lds(
      (const __attribute__((address_space(1))) void*)g,
      (__attribute__((address_space(3))) void*)l, 16, 0, 0);
}

// ---------------- weights fp32 -> bf16, order [Wq | Wk*c1 | Wv*c1 | Wk | Wv | Wo] ----------------
__global__ __launch_bounds__(256) void cvt_weights6(
    const float* __restrict__ wq, const float* __restrict__ wk,
    const float* __restrict__ wv, const float* __restrict__ wo,
    const float* __restrict__ c1, bf16* __restrict__ dst) {
  const size_t i = (size_t)blockIdx.x * 256 + threadIdx.x;  // float4 index
  const size_t per = WE / 4;
  if (i >= 6 * per) return;
  const int region = (int)(i / per);
  const size_t within = i % per;
  const float* srcs[6] = {wq, wk, wv, wk, wv, wo};
  const float4 f = ((const float4*)srcs[region])[within];
  float v[4] = {f.x, f.y, f.z, f.w};
  if (region == 1 || region == 2) {
    const int c0 = (int)((within * 4) % DIM);
#pragma unroll
    for (int j = 0; j < 4; ++j) v[j] *= c1[c0 + j];
  }
  bf16* o = dst + i * 4;
#pragma unroll
  for (int j = 0; j < 4; ++j) o[j] = (bf16)v[j];
}

// ---------------- hs fp32 -> bf16 ----------------
__global__ __launch_bounds__(256) void cvt_hs(const float* __restrict__ src,
                                              bf16* __restrict__ dst, int n4) {
  const int i = blockIdx.x * 256 + threadIdx.x;
  if (i >= n4) return;
  const float4 f = ((const float4*)src)[i];
  bf16* o = dst + (size_t)i * 4;
  o[0] = (bf16)f.x; o[1] = (bf16)f.y; o[2] = (bf16)f.z; o[3] = (bf16)f.w;
}

// ---------------- depthwise conv + cls concat -> xb bf16 [B][L][768] ----------------
template <int KS>
__global__ __launch_bounds__(256) void conv_kernel(
    const float* __restrict__ hs, const float* __restrict__ cw, bf16* __restrict__ xb) {
  constexpr int OW = 17 - KS;
  constexpr int NOUT = OW * OW;
  constexpr int L = NOUT + 1;
  constexpr int KSQ = KS * KS;
  constexpr int NP = (NOUT + 7) / 8;
  __shared__ float hsl[256][36];
  __shared__ float wsm[32][KSQ];

  const int t = threadIdx.x;
  const int b = blockIdx.y;
  const int c0 = blockIdx.x * 32;

  const float* src = hs + ((size_t)b * SEQ + 1 + t) * DIM + c0;
#pragma unroll
  for (int j = 0; j < 8; ++j) *(float4*)&hsl[t][4 * j] = ((const float4*)src)[j];

  if (t < 32) {
#pragma unroll
    for (int q = 0; q < KSQ; ++q) wsm[t][q] = cw[(size_t)(c0 + t) * KSQ + q];
    const float cv = hs[(size_t)b * SEQ * DIM + c0 + t];
    xb[(size_t)b * L * DIM + c0 + t] = (bf16)cv;
  }
  __syncthreads();

  const int c = t & 31, pg = t >> 5;
#pragma unroll
  for (int i = 0; i < NP; ++i) {
    const int p = pg * NP + i;
    if (p < NOUT) {
      const int oi = p / OW, oj = p - oi * OW;
      float a = 0.f;
#pragma unroll
      for (int di = 0; di < KS; ++di)
#pragma unroll
        for (int dj = 0; dj < KS; ++dj)
          a += hsl[(oi + di) * 16 + oj + dj][c] * wsm[c][di * KS + dj];
      xb[((size_t)b * L + 1 + p) * DIM + c0 + c] = (bf16)a;
    }
  }
}

// ---------------- GEMM core: 128x256 tile, 512 threads (8 waves = 2x4 of 64x64) ----------------
// 3 LDS buffers (72 KB, 2 blocks/CU = 16 waves/CU), stage kt+2 while computing kt,
// counted s_waitcnt vmcnt(3) (3 loads/thread/stage, never 0 mid-loop) + s_barrier.
// Both-sides chunk swizzle. LDS-staged epilogue for bf16 outputs.
// OUT: 1 = KV (N=1536: tN<3 K, >=3 V); 3 = fp32 [M][768]; 4 = QKV (N=2304: Q/K/V per 3).
template <int OUT>
__device__ __forceinline__ void gemm_core(
    bf16* sm, const bf16* A, const bf16* W,
    const float* b0, const float* b1, const float* b2,
    void* Y0, void* Y1, void* Y2, int M, int L, int Lv, int tM, int tN, int tid) {
  constexpr int A_E = 128 * 32;  // 4096 elems / buffer
  constexpr int B_E = 256 * 32;  // 8192 elems / buffer
  bf16* smA = sm;                // 3 buffers A
  bf16* smB = sm + 3 * A_E;      // 3 buffers B

  const int lane = tid & 63;
  const int w = tid >> 6;            // 0..7
  const int wrow = (w >> 2) * 64;    // 0,64
  const int wcol = (w & 3) * 64;     // 0,64,128,192
  const int rl = lane & 15;
  const int g = lane >> 4;
  const int kqs = ((g ^ ((rl >> 1) & 3)) << 3);  // read-side chunk deswizzle

  const int sr = lane >> 2;
  const int sk = (((lane & 3) ^ ((sr >> 1) & 3)) << 3);  // staging global pre-swizzle
  // wave w stages: A rows [w*16, w*16+16); B rows [(2w)*16, (2w+2)*16)
  long gar = (long)tM * 128 + w * 16 + sr; if (gar >= M) gar = M - 1;
  const bf16* pa  = A + gar * DIM + sk;
  const bf16* pb0 = W + ((size_t)tN * 256 + (2 * w) * 16 + sr) * DIM + sk;
  const bf16* pb1 = W + ((size_t)tN * 256 + (2 * w + 1) * 16 + sr) * DIM + sk;
  const int la  = w * 512;             // wave-uniform elem offsets within buffer
  const int lb0 = (2 * w) * 512;
  const int lb1 = (2 * w + 1) * 512;

  const f32x4 zero4 = {0.f, 0.f, 0.f, 0.f};
  f32x4 acc[4][4];
#pragma unroll
  for (int m = 0; m < 4; ++m)
#pragma unroll
    for (int n = 0; n < 4; ++n) acc[m][n] = zero4;

  constexpr int NT = DIM / 32;  // 24 K-steps

#define STAGE(kt_, buf_)                                      \
  do {                                                        \
    const int kb_ = (kt_) * 32;                               \
    gload_lds16(pa  + kb_, smA + (buf_) * A_E + la);          \
    gload_lds16(pb0 + kb_, smB + (buf_) * B_E + lb0);         \
    gload_lds16(pb1 + kb_, smB + (buf_) * B_E + lb1);         \
  } while (0)

  STAGE(0, 0);
  STAGE(1, 1);
  asm volatile("s_waitcnt vmcnt(3)" ::: "memory");
  __builtin_amdgcn_s_barrier();
  __builtin_amdgcn_sched_barrier(0);

  int buf = 0;
  for (int kt = 0; kt < NT; ++kt) {
    const bf16* Ac = smA + buf * A_E;
    const bf16* Bc = smB + buf * B_E;
    bf16x8 af[4], bfr[4];
#pragma unroll
    for (int m = 0; m < 4; ++m) af[m] = *(const bf16x8*)&Ac[(wrow + m * 16 + rl) * 32 + kqs];
#pragma unroll
    for (int n = 0; n < 4; ++n) bfr[n] = *(const bf16x8*)&Bc[(wcol + n * 16 + rl) * 32 + kqs];
#pragma unroll
    for (int m = 0; m < 4; ++m)
#pragma unroll
      for (int n = 0; n < 4; ++n) acc[m][n] = MFMA_BF16(af[m], bfr[n], acc[m][n]);

    if (kt + 2 < NT) {
      const int nb = buf + 2 >= 3 ? buf - 1 : buf + 2;
      STAGE(kt + 2, nb);
    }
    if (kt + 1 < NT) {
      if (kt + 2 < NT) asm volatile("s_waitcnt vmcnt(3)" ::: "memory");
      else             asm volatile("s_waitcnt vmcnt(0)" ::: "memory");
      __builtin_amdgcn_s_barrier();
      __builtin_amdgcn_sched_barrier(0);
    }
    buf = buf == 2 ? 0 : buf + 1;
  }
#undef STAGE

  // ---------------- epilogue ----------------
  if constexpr (OUT == 3) {
#pragma unroll
    for (int n = 0; n < 4; ++n) {
      const int gcol = tN * 256 + wcol + n * 16 + rl;
      const float bia = b0[gcol];
#pragma unroll
      for (int m = 0; m < 4; ++m) {
#pragma unroll
        for (int i = 0; i < 4; ++i) {
          const long grow = (long)tM * 128 + wrow + m * 16 + g * 4 + i;
          if (grow < M) ((float*)Y0)[grow * DIM + gcol] = acc[m][n][i] + bia;
        }
      }
    }
    return;
  }

  bf16* smT = sm;
  __syncthreads();  // all compute + DMA done; sm reusable (36864 elems available)

  const bool qpath = (OUT == 4) && (tN < 3);
  const bool vpath = (OUT == 4) ? (tN >= 6) : (tN >= 3);

  if (vpath) {
    constexpr int TPV = 136;  // row stride pad (col-major store)
    const int cbase = (OUT == 4) ? 1536 : 768;
    const float* bv_ = (OUT == 4) ? b2 : b1;
#pragma unroll
    for (int n = 0; n < 4; ++n) {
      const int col = wcol + n * 16 + rl;
      const float bia = bv_[tN * 256 + col - cbase];
#pragma unroll
      for (int m = 0; m < 4; ++m) {
        const int row = wrow + m * 16 + g * 4;
        bf16x4 v4;
#pragma unroll
        for (int i = 0; i < 4; ++i) v4[i] = (bf16)(acc[m][n][i] + bia);
        *(bf16x4*)(smT + col * TPV + row) = v4;
      }
    }
    __syncthreads();
    bf16* vout = (bf16*)((OUT == 4) ? Y2 : Y1);
    const int tNv = tN - ((OUT == 4) ? 6 : 3);
#pragma unroll
    for (int it = 0; it < 8; ++it) {
      const int c = it * 512 + tid;     // 4096 chunks: 256 cols x 16 row-chunks
      const int coll = c >> 4;
      const int rw0 = (c & 15) * 8;
      const long g2 = (long)tM * 128 + rw0;
      if (g2 < M) {
        const int b2i = (int)(g2 / L);
        const int l2 = (int)(g2 - (long)b2i * L);
        const int cv = tNv * 256 + coll;
        bf16* dst = vout + (((size_t)b2i * NH + (cv >> 6)) * 64 + (cv & 63)) * Lv;
        const bf16x8 v = *(const bf16x8*)(smT + coll * TPV + rw0);
        if (l2 + 8 <= L) {
          *(bf16x8*)(dst + l2) = v;
        } else {
#pragma unroll
          for (int j = 0; j < 8; ++j) {
            const long g3 = g2 + j;
            const int b3 = (int)(g3 / L), l3 = (int)(g3 - (long)b3 * L);
            vout[(((size_t)b3 * NH + (cv >> 6)) * 64 + (cv & 63)) * Lv + l3] = v[j];
          }
        }
      }
    }
  } else {
    constexpr int TPK = 264;  // col stride pad (row-major store)
    const float scale = qpath ? 0.125f : 1.f;
#pragma unroll
    for (int n = 0; n < 4; ++n) {
      const int col = wcol + n * 16 + rl;
      const int gcol = tN * 256 + col;
      float bia;
      if constexpr (OUT == 4) bia = qpath ? b0[gcol] : b1[gcol - 768];
      else                    bia = b0[gcol];
#pragma unroll
      for (int m = 0; m < 4; ++m) {
#pragma unroll
        for (int i = 0; i < 4; ++i) {
          const int row = wrow + m * 16 + g * 4 + i;
          smT[row * TPK + col] = (bf16)((acc[m][n][i] + bia) * scale);
        }
      }
    }
    __syncthreads();
    bf16* kout = (bf16*)(qpath ? Y0 : ((OUT == 4) ? Y1 : Y0));
    const int coff = (OUT == 4 && !qpath) ? 768 : 0;
    const bool kswz = !qpath;  // K outputs chunk-swizzled for attn's linear DMA
#pragma unroll
    for (int it = 0; it < 8; ++it) {
      const int c = it * 512 + tid;     // 4096 chunks: 128 rows x 32 col-chunks
      const int row = c >> 5;
      const int col0 = (c & 31) * 8;
      const long g2 = (long)tM * 128 + row;
      if (g2 < M) {
        const int b2i = (int)(g2 / L);
        const int l2 = (int)(g2 - (long)b2i * L);
        const int gc = tN * 256 + col0 - coff;
        const bf16x8 v = *(const bf16x8*)(smT + row * TPK + col0);
        if (qpath) {
          *(bf16x8*)(kout + (((size_t)b2i * NH + (gc >> 6)) * 257 + l2) * 64 + (gc & 63)) = v;
        } else {
          int dchunk = (gc & 63) >> 3;
          if (kswz) dchunk ^= (l2 & 7);
          *(bf16x8*)(kout + (((size_t)b2i * NH + (gc >> 6)) * L + l2) * 64 + dchunk * 8) = v;
        }
      }
    }
  }
}

__device__ __forceinline__ int m204_swz(int orig, int nwg) {
  const int nq = nwg >> 3, rr = nwg & 7, xcd = orig & 7, base = orig >> 3;
  return (xcd < rr ? xcd * (nq + 1) : rr * (nq + 1) + (xcd - rr) * nq) + base;
}

// ---- QKV0 mega-GEMM: A=hs_bf16, W=[Wq|Wk*c1|Wv*c1], N=2304, nN=9 ----
__global__ __launch_bounds__(512, 4) void gemm_qkv0_kernel(
    const bf16* __restrict__ A, const bf16* __restrict__ W,
    const float* __restrict__ bq, const float* __restrict__ bk, const float* __restrict__ bv,
    bf16* __restrict__ qb, bf16* __restrict__ kb, bf16* __restrict__ vb) {
  __shared__ alignas(16) bf16 sm[36864];
  const int wgid = m204_swz(blockIdx.x, gridDim.x);
  const int tM = wgid / 9, tN = wgid - tM * 9;
  gemm_core<4>(sm, A, W, bq, bk, bv, qb, kb, vb, BATCH * SEQ, 257, 264, tM, tN, threadIdx.x);
}

// ---- fused KV1+KV2 GEMM: [0,594) branch1 (99x6), [594,1032) branch2 (73x6) ----
__global__ __launch_bounds__(512, 4) void gemm_kv12_kernel(
    const bf16* __restrict__ A1, const bf16* __restrict__ A2, const bf16* __restrict__ W,
    const float* __restrict__ bk, const float* __restrict__ bv,
    bf16* __restrict__ k1, bf16* __restrict__ v1,
    bf16* __restrict__ k2, bf16* __restrict__ v2) {
  __shared__ alignas(16) bf16 sm[36864];
  const int wgid = m204_swz(blockIdx.x, gridDim.x);
  if (wgid < 594) {
    const int tM = wgid / 6, tN = wgid - tM * 6;
    gemm_core<1>(sm, A1, W, bk, bv, nullptr, k1, v1, nullptr, BATCH * 197, 197, 200, tM, tN, threadIdx.x);
  } else {
    const int l = wgid - 594;
    const int tM = l / 6, tN = l - tM * 6;
    gemm_core<1>(sm, A2, W, bk, bv, nullptr, k2, v2, nullptr, BATCH * 145, 145, 152, tM, tN, threadIdx.x);
  }
}

// ---- O projection: N=768, nN=3 ----
__global__ __launch_bounds__(512, 4) void gemm_o_kernel(
    const bf16* __restrict__ A, const bf16* __restrict__ W,
    const float* __restrict__ bo, float* __restrict__ out) {
  __shared__ alignas(16) bf16 sm[36864];
  const int wgid = m204_swz(blockIdx.x, gridDim.x);
  const int tM = wgid / 3, tN = wgid - tM * 3;
  gemm_core<3>(sm, A, W, bo, nullptr, nullptr, out, nullptr, nullptr, BATCH * SEQ, 257, 1, tM, tN, threadIdx.x);
}

// ---- cls fixup: branch-0 K/V row l=0 must use UNSCALED Wk/Wv ----
__global__ __launch_bounds__(256) void cls_fixup_kernel(
    const bf16* __restrict__ hsb, const bf16* __restrict__ wk, const bf16* __restrict__ wv,
    const float* __restrict__ bk, const float* __restrict__ bv,
    bf16* __restrict__ k12, bf16* __restrict__ v12) {
  __shared__ float hrow[DIM];
  const int b = blockIdx.y, tile = blockIdx.x, t = threadIdx.x;
  for (int i = t; i < DIM; i += 256) hrow[i] = (float)hsb[(size_t)b * SEQ * DIM + i];
  __syncthreads();
  const bool isv = tile >= 6;
  const int o = (tile - (isv ? 6 : 0)) * 128 + (t >> 1);
  const int half = t & 1;
  const bf16* wrow = (isv ? wv : wk) + (size_t)o * DIM + half * 384;
  float s = 0.f;
#pragma unroll 4
  for (int k = 0; k < 48; ++k) {
    const bf16x8 wv8 = *(const bf16x8*)(wrow + k * 8);
#pragma unroll
    for (int j = 0; j < 8; ++j) s += hrow[half * 384 + k * 8 + j] * (float)wv8[j];
  }
  s += __shfl_xor(s, 1);
  if (!half) {
    s += (isv ? bv : bk)[o];
    if (!isv) {
      k12[(((size_t)b * NH + (o >> 6)) * 257) * 64 + (o & 63)] = (bf16)s;  // l=0: swizzle identity
    } else {
      v12[(((size_t)b * NH + (o >> 6)) * 64 + (o & 63)) * 264] = (bf16)s;
    }
  }
}

// ---------------- fused attention: one block per (b,h), loops over 5 q-tiles ----------------
template <int L, int BRANCH>
__global__ __launch_bounds__(256, 2) void attn_kernel(
    const bf16* __restrict__ qb, const bf16* __restrict__ kb, const bf16* __restrict__ vb,
    float* __restrict__ ctx, bf16* __restrict__ xbuf, int Lv) {
  constexpr int LK16 = (L + 15) & ~15;
  constexpr int NKT = LK16 / 16;
  constexpr int LP32 = (L + 31) & ~31;
  constexpr int NK32 = LP32 / 32;
  constexpr int PSTR = LP32 + 8;
  __shared__ alignas(16) bf16 Ks[LK16 * 64];
  __shared__ alignas(16) bf16 Ps[64 * PSTR];

  const int tid = threadIdx.x, lane = tid & 63, w = tid >> 6;
  const int orig = blockIdx.x;
  const int nper = gridDim.x >> 3;
  const int bh = (orig & 7) * nper + (orig >> 3);
  const int b = bh / NH, h = bh % NH;
  const int cl = lane & 15, g = lane >> 4;

  const bf16* kbase = kb + (size_t)bh * L * 64;
  for (int c = tid; c < LK16 * 8; c += 256)
    gload_lds16(kbase + (size_t)c * 8, Ks + (size_t)c * 8);
  __syncthreads();

  const bf16* vbase = vb + (size_t)bh * 64 * Lv;

  for (int qt = 0; qt < 5; ++qt) {
    int sq = qt * 64 + w * 16 + cl;
    if (sq > 256) sq = 256;
    const bf16* qrow = qb + ((size_t)bh * 257 + sq) * 64 + g * 8;
    const bf16x8 aq0 = *(const bf16x8*)qrow;
    const bf16x8 aq1 = *(const bf16x8*)(qrow + 32);

    float sums[4] = {0.f, 0.f, 0.f, 0.f};
    const int prow0 = (w * 16 + g * 4) * PSTR + cl;
#pragma unroll
    for (int kt = 0; kt < NKT; ++kt) {
      const int key0 = kt * 16 + cl;
      const int sw = key0 & 7;
      const char* krow = (const char*)Ks + key0 * 128;
      const bf16x8 bk0 = *(const bf16x8*)(krow + ((g ^ sw) << 4));
      const bf16x8 bk1 = *(const bf16x8*)(krow + (((4 + g) ^ sw) << 4));
      f32x4 z = {0.f, 0.f, 0.f, 0.f};
      z = MFMA_BF16(aq0, bk0, z);
      z = MFMA_BF16(aq1, bk1, z);
      const bool valid = key0 < L;
#pragma unroll
      for (int j = 0; j < 4; ++j) {
        const float p = valid ? __expf(z[j]) : 0.f;
        sums[j] += p;
        Ps[prow0 + j * PSTR + kt * 16] = (bf16)p;
      }
    }
    if constexpr (LP32 > LK16) {
#pragma unroll
      for (int j = 0; j < 4; ++j) Ps[prow0 + j * PSTR + LK16] = (bf16)0.f;
    }

    bf16x8 vr0[4], vr1[4];
#pragma unroll
    for (int nt = 0; nt < 4; ++nt)
      vr0[nt] = *(const bf16x8*)(vbase + (size_t)(nt * 16 + cl) * Lv + g * 8);

#pragma unroll
    for (int j = 0; j < 4; ++j) {
      sums[j] += __shfl_xor(sums[j], 1);
      sums[j] += __shfl_xor(sums[j], 2);
      sums[j] += __shfl_xor(sums[j], 4);
      sums[j] += __shfl_xor(sums[j], 8);
    }
    float inv[4];
#pragma unroll
    for (int j = 0; j < 4; ++j) inv[j] = 1.f / sums[j];

    f32x4 cacc[4];
#pragma unroll
    for (int nt = 0; nt < 4; ++nt) cacc[nt] = f32x4{0.f, 0.f, 0.f, 0.f};
#pragma unroll
    for (int kt = 0; kt < NK32; ++kt) {
      const bool even = (kt & 1) == 0;
      if (kt + 1 < NK32) {
        int kk = (kt + 1) * 32 + g * 8;
        if (kk > Lv - 8) kk = Lv - 8;
#pragma unroll
        for (int nt = 0; nt < 4; ++nt) {
          const bf16x8 v = *(const bf16x8*)(vbase + (size_t)(nt * 16 + cl) * Lv + kk);
          if (even) vr1[nt] = v; else vr0[nt] = v;
        }
      }
      const bf16x8 ap = *(const bf16x8*)&Ps[(w * 16 + cl) * PSTR + kt * 32 + g * 8];
#pragma unroll
      for (int nt = 0; nt < 4; ++nt)
        cacc[nt] = MFMA_BF16(ap, even ? vr0[nt] : vr1[nt], cacc[nt]);
    }

#pragma unroll
    for (int nt = 0; nt < 4; ++nt) {
#pragma unroll
      for (int i = 0; i < 4; ++i) {
        const int s_q = qt * 64 + w * 16 + g * 4 + i;
        if (s_q < 257) {
          const size_t idx = ((size_t)b * 257 + s_q) * DIM + h * 64 + nt * 16 + cl;
          const float val = cacc[nt][i] * inv[i];
          if constexpr (BRANCH == 0)
            ctx[idx] = val;
          else if constexpr (BRANCH == 1)
            ctx[idx] += val;
          else
            xbuf[idx] = (bf16)((ctx[idx] + val) * (1.f / 3.f));
        }
      }
    }
  }
}

extern "C" void kernel_launch(void* const* d_in, const int* in_sizes, int n_in,
                              void* d_out, int out_size, void* d_ws, size_t ws_size,
                              hipStream_t stream) {
  (void)in_sizes; (void)n_in; (void)out_size; (void)ws_size;
  const float* hs = (const float*)d_in[0];
  const float* Wq = (const float*)d_in[1];
  const float* bq = (const float*)d_in[2];
  const float* Wk = (const float*)d_in[3];
  const float* bk = (const float*)d_in[4];
  const float* Wv = (const float*)d_in[5];
  const float* bv = (const float*)d_in[6];
  const float* Wo = (const float*)d_in[7];
  const float* bo = (const float*)d_in[8];
  const float* c1 = (const float*)d_in[9];
  const float* c2 = (const float*)d_in[10];
  const float* c3 = (const float*)d_in[11];
  float* out = (float*)d_out;

  constexpr size_t QB = (size_t)BATCH * NH * SEQ * 64;
  constexpr size_t XB = (size_t)BATCH * SEQ * DIM;
  constexpr size_t K12 = (size_t)BATCH * NH * 257 * 64;
  constexpr size_t V12 = (size_t)BATCH * NH * 64 * 264;
  constexpr size_t XB3 = (size_t)BATCH * 145 * DIM;
  constexpr size_t K3 = (size_t)BATCH * NH * 145 * 64;

  bf16* wbf = (bf16*)d_ws;           // [Wq|Wk*c1|Wv*c1|Wk|Wv|Wo] 6*WE
  bf16* qb  = wbf + 6 * WE;
  bf16* xb  = qb + QB;               // hsb, later conv2 output; finally ctx/3 bf16
  bf16* k12 = xb + XB;               // branch0 K, later branch1 K
  bf16* v12 = k12 + K12;             // branch0 V, later branch1 V
  bf16* xb3 = v12 + V12;             // conv3 output
  bf16* k3  = xb3 + XB3;
  bf16* v3  = k3 + K3;
  bf16* hsb = xb;

  cvt_weights6<<<dim3((unsigned)((6 * WE / 4 + 255) / 256)), 256, 0, stream>>>(Wq, Wk, Wv, Wo, c1, wbf);
  cvt_hs<<<dim3((BATCH * SEQ * DIM / 4 + 255) / 256), 256, 0, stream>>>(hs, hsb, BATCH * SEQ * DIM / 4);

  // ---- branch 0 (1x1 conv folded into weights): Q, K0, V0 in one GEMM + cls fixup ----
  gemm_qkv0_kernel<<<dim3(129 * 9), 512, 0, stream>>>(hsb, wbf, bq, bk, bv, qb, k12, v12);
  cls_fixup_kernel<<<dim3(12, 64), 256, 0, stream>>>(hsb, wbf + 3 * WE, wbf + 4 * WE, bk, bv, k12, v12);
  attn_kernel<257, 0><<<dim3(768), 256, 0, stream>>>(qb, k12, v12, out, xb, 264);

  // ---- branches 1 & 2: convs, fused KV GEMM, attns ----
  conv_kernel<3><<<dim3(24, 64), 256, 0, stream>>>(hs, c2, xb);
  conv_kernel<5><<<dim3(24, 64), 256, 0, stream>>>(hs, c3, xb3);
  gemm_kv12_kernel<<<dim3(594 + 438), 512, 0, stream>>>(xb, xb3, wbf + 3 * WE, bk, bv,
                                                        k12, v12, k3, v3);
  attn_kernel<197, 1><<<dim3(768), 256, 0, stream>>>(qb, k12, v12, out, xb, 200);
  attn_kernel<145, 2><<<dim3(768), 256, 0, stream>>>(qb, k3, v3, out, xb, 152);

  // ---- output projection ----
  gemm_o_kernel<<<dim3(129 * 3), 512, 0, stream>>>(xb, wbf + 5 * WE, bo, out);
}